// Round 13
// baseline (392.726 us; speedup 1.0000x reference)
//
#include <hip/hip_runtime.h>
#include <hip/hip_bf16.h>
#include <stdint.h>

typedef __bf16 bf16x8 __attribute__((ext_vector_type(8)));
typedef float f32x4 __attribute__((ext_vector_type(4)));
typedef unsigned short ushort_t;

static constexpr int kB = 16;
static constexpr int kN = 3137;           // 1 + 56*56
static constexpr long kM = (long)kB * kN; // 50192
static constexpr int kNS = 64;            // tvec n-split

__device__ __forceinline__ float bf2f(ushort_t u) {
  return __uint_as_float(((unsigned)u) << 16);
}
__device__ __forceinline__ ushort_t f2bf(float f) {
  __hip_bfloat16 h = __float2bfloat16(f);
  return *reinterpret_cast<ushort_t*>(&h);
}
__device__ __forceinline__ void gload16(const void* g, void* l) {
  __builtin_amdgcn_global_load_lds(
      (const __attribute__((address_space(1))) unsigned int*)g,
      (__attribute__((address_space(3))) unsigned int*)(uintptr_t)l,
      16, 0, 0);
}
__device__ __forceinline__ f32x4 mfma16(bf16x8 a, bf16x8 b, f32x4 c) {
  return __builtin_amdgcn_mfma_f32_16x16x32_bf16(a, b, c, 0, 0, 0);
}

// ---------------- prep kernels (launch-fused) ----------------

__global__ __launch_bounds__(256) void cast3_kernel(
    const float* __restrict__ wf, const float* __restrict__ w1,
    const float* __restrict__ w2, ushort_t* __restrict__ wf_bf,
    ushort_t* __restrict__ w1_bf, ushort_t* __restrict__ w2_bf) {
  long i = (long)blockIdx.x * 256 + threadIdx.x;  // over 262144 chunks
  const float* s;
  ushort_t* d;
  long o;
  if (i < 131072) { s = wf; d = wf_bf; o = i; }
  else if (i < 196608) { s = w1; d = w1_bf; o = i - 131072; }
  else { s = w2; d = w2_bf; o = i - 196608; }
  float4 v = *(const float4*)(s + o * 4);
  ushort4 u;
  u.x = f2bf(v.x); u.y = f2bf(v.y); u.z = f2bf(v.z); u.w = f2bf(v.w);
  *(ushort4*)(d + o * 4) = u;
}

__global__ __launch_bounds__(256) void transpose_cast_kernel(
    const float* __restrict__ srcA, ushort_t* __restrict__ dstA,
    const float* __restrict__ srcB, ushort_t* __restrict__ dstB, int R, int C) {
  __shared__ float tile[32][33];
  const float* src = (blockIdx.z == 0) ? srcA : srcB;
  ushort_t* dst = (blockIdx.z == 0) ? dstA : dstB;
  const int tx = blockIdx.x * 32, ty = blockIdx.y * 32;
  const int x = threadIdx.x & 31, y0 = threadIdx.x >> 5;
#pragma unroll
  for (int j = 0; j < 32; j += 8)
    tile[y0 + j][x] = src[(long)(ty + y0 + j) * C + tx + x];
  __syncthreads();
#pragma unroll
  for (int j = 0; j < 32; j += 8)
    dst[(long)(tx + y0 + j) * R + ty + x] = f2bf(tile[x][y0 + j]);
}

__global__ __launch_bounds__(256) void gemv5_kernel(
    const ushort_t* __restrict__ wqT, const ushort_t* __restrict__ wkT,
    const ushort_t* __restrict__ wf_bf, const float* __restrict__ bq,
    const float* __restrict__ bk, const float* __restrict__ wg,
    const float* __restrict__ bp, const float* __restrict__ bfv,
    float* __restrict__ uq, float* __restrict__ uk, float* __restrict__ vg,
    float* __restrict__ cfq, float* __restrict__ cvec) {
  const int job = blockIdx.y;
  const ushort_t* A = (job == 0 || job == 2) ? wqT : (job == 1 ? wkT : wf_bf);
  const float* v = (job == 0 || job == 3) ? bq : (job == 1 ? bk : (job == 2 ? wg : bp));
  float* out = job == 0 ? uq : job == 1 ? uk : job == 2 ? vg : job == 3 ? cfq : cvec;
  int row = blockIdx.x * 4 + (threadIdx.x >> 6);
  if (row >= 256) return;
  int lane = threadIdx.x & 63;
  float acc = 0.f;
  for (int k0 = lane * 8; k0 < 2048; k0 += 512) {
    uint4 raw = *(const uint4*)(A + (long)row * 2048 + k0);
    const ushort_t* u = (const ushort_t*)&raw;
#pragma unroll
    for (int j = 0; j < 8; ++j) acc += bf2f(u[j]) * v[k0 + j];
  }
#pragma unroll
  for (int o = 32; o >= 1; o >>= 1) acc += __shfl_xor(acc, o);
  if (lane == 0) out[row] = (job == 4 ? bfv[row] : 0.f) + acc;
}

__global__ __launch_bounds__(256) void gemv_kernel(const ushort_t* __restrict__ A,
                                                   const float* __restrict__ v,
                                                   float* __restrict__ out, int rows,
                                                   int K) {
  int row = blockIdx.x * 4 + (threadIdx.x >> 6);
  if (row >= rows) return;
  int lane = threadIdx.x & 63;
  float acc = 0.f;
  for (int k0 = lane * 8; k0 < K; k0 += 512) {
    uint4 raw = *(const uint4*)(A + (long)row * K + k0);
    const ushort_t* u = (const ushort_t*)&raw;
#pragma unroll
    for (int j = 0; j < 8; ++j) acc += bf2f(u[j]) * v[k0 + j];
  }
#pragma unroll
  for (int o = 32; o >= 1; o >>= 1) acc += __shfl_xor(acc, o);
  if (lane == 0) out[row] = acc;
}

__global__ __launch_bounds__(256) void scalars_kernel(const float* __restrict__ bq,
                                                      const float* __restrict__ bk,
                                                      const float* __restrict__ wg,
                                                      float* __restrict__ scal) {
  __shared__ float red[3][4];
  float s0 = 0, s1 = 0, s2 = 0;
  for (int i = threadIdx.x; i < 2048; i += 256) {
    s0 += bq[i] * bq[i];
    s1 += bk[i] * bk[i];
    s2 += bq[i] * wg[i];
  }
#pragma unroll
  for (int o = 32; o >= 1; o >>= 1) {
    s0 += __shfl_xor(s0, o); s1 += __shfl_xor(s1, o); s2 += __shfl_xor(s2, o);
  }
  int w = threadIdx.x >> 6;
  if ((threadIdx.x & 63) == 0) { red[0][w] = s0; red[1][w] = s1; red[2][w] = s2; }
  __syncthreads();
  if (threadIdx.x < 3)
    scal[threadIdx.x] = red[threadIdx.x][0] + red[threadIdx.x][1] +
                        red[threadIdx.x][2] + red[threadIdx.x][3];
}

__global__ __launch_bounds__(256) void ln_kernel(
    const float* __restrict__ x, const float* __restrict__ gw,
    const float* __restrict__ gb, ushort_t* __restrict__ out, long M,
    const float* __restrict__ uqv, const float* __restrict__ ukv,
    const float* __restrict__ vgv, float* __restrict__ duq,
    float* __restrict__ duk, float* __restrict__ dvg) {
  long row = (long)blockIdx.x * 4 + (threadIdx.x >> 6);
  if (row >= M) return;
  int lane = threadIdx.x & 63;
  float4 v = *(const float4*)(x + row * 256 + lane * 4);
  float s = v.x + v.y + v.z + v.w;
  float s2 = v.x * v.x + v.y * v.y + v.z * v.z + v.w * v.w;
#pragma unroll
  for (int o = 32; o >= 1; o >>= 1) {
    s += __shfl_xor(s, o);
    s2 += __shfl_xor(s2, o);
  }
  float mu = s * (1.f / 256.f);
  float var = fmaxf(s2 * (1.f / 256.f) - mu * mu, 0.f);
  float rsd = rsqrtf(var + 1e-5f);
  float e[4];
  ushort4 o4;
  e[0] = bf2f(o4.x = f2bf((v.x - mu) * rsd * gw[lane * 4 + 0] + gb[lane * 4 + 0]));
  e[1] = bf2f(o4.y = f2bf((v.y - mu) * rsd * gw[lane * 4 + 1] + gb[lane * 4 + 1]));
  e[2] = bf2f(o4.z = f2bf((v.z - mu) * rsd * gw[lane * 4 + 2] + gb[lane * 4 + 2]));
  e[3] = bf2f(o4.w = f2bf((v.w - mu) * rsd * gw[lane * 4 + 3] + gb[lane * 4 + 3]));
  *(ushort4*)(out + row * 256 + lane * 4) = o4;
  if (duq) {
    int base = lane * 4;
    float a = e[0] * uqv[base] + e[1] * uqv[base + 1] + e[2] * uqv[base + 2] + e[3] * uqv[base + 3];
    float b = e[0] * ukv[base] + e[1] * ukv[base + 1] + e[2] * ukv[base + 2] + e[3] * ukv[base + 3];
    float c = e[0] * vgv[base] + e[1] * vgv[base + 1] + e[2] * vgv[base + 2] + e[3] * vgv[base + 3];
#pragma unroll
    for (int o = 32; o >= 1; o >>= 1) {
      a += __shfl_xor(a, o); b += __shfl_xor(b, o); c += __shfl_xor(c, o);
    }
    if (lane == 0) { duq[row] = a; duk[row] = b; dvg[row] = c; }
  }
}

__global__ __launch_bounds__(256) void reduce_rows_kernel(
    const float* __restrict__ part, const float* __restrict__ duq,
    const float* __restrict__ duk, const float* __restrict__ dvg,
    const float* __restrict__ scal, float* __restrict__ rs_q,
    float* __restrict__ rs_k, float* __restrict__ Av) {
  long i = (long)blockIdx.x * 256 + threadIdx.x;
  if (i >= kM) return;
  float sq = 0.f, sk = 0.f;
#pragma unroll
  for (int s = 0; s < 8; ++s) sq += part[(long)s * kM + i];
#pragma unroll
  for (int s = 8; s < 16; ++s) sk += part[(long)s * kM + i];
  sq += 2.f * duq[i] + scal[0];
  sk += 2.f * duk[i] + scal[1];
  float rq = 1.f / fmaxf(sqrtf(fmaxf(sq, 0.f)), 1e-12f);
  float rk = 1.f / fmaxf(sqrtf(fmaxf(sk, 0.f)), 1e-12f);
  rs_q[i] = rq;
  rs_k[i] = rk;
  Av[i] = rq * (dvg[i] + scal[2]) * 0.0625f;
}

__global__ __launch_bounds__(256) void anorm_kernel(const float* __restrict__ Av,
                                                    float* __restrict__ invA) {
  int b = blockIdx.x;
  __shared__ float red[4];
  float s = 0.f;
  for (int n = threadIdx.x; n < kN; n += 256) {
    float a = Av[(long)b * kN + n];
    s += a * a;
  }
#pragma unroll
  for (int o = 32; o >= 1; o >>= 1) s += __shfl_xor(s, o);
  if ((threadIdx.x & 63) == 0) red[threadIdx.x >> 6] = s;
  __syncthreads();
  if (threadIdx.x == 0)
    invA[b] = 1.f / fmaxf(sqrtf(red[0] + red[1] + red[2] + red[3]), 1e-12f);
}

__global__ __launch_bounds__(256) void tvec_kernel(const ushort_t* __restrict__ xn,
                                                   const float* __restrict__ Av,
                                                   const float* __restrict__ rs_q,
                                                   const float* __restrict__ invA,
                                                   float* __restrict__ tpart,
                                                   float* __restrict__ Spart) {
  const int ns = blockIdx.x, b = blockIdx.y;
  const int n0 = ns * 50;
  int cnt = kN - n0; if (cnt > 50) cnt = 50; if (cnt < 0) cnt = 0;
  __shared__ float c_lds[50];
  const int t = threadIdx.x;
  if (t < cnt) {
    long gi = (long)b * kN + n0 + t;
    c_lds[t] = invA[b] * Av[gi] * rs_q[gi];
  }
  __syncthreads();
  float acc = 0.f;
  const ushort_t* p = xn + ((long)b * kN + n0) * 256 + t;
  for (int i = 0; i < cnt; ++i, p += 256) acc += c_lds[i] * bf2f(*p);
  tpart[((long)ns * 16 + b) * 256 + t] = acc;
  if (t == 0) {
    float s = 0.f;
    for (int i = 0; i < cnt; ++i) s += c_lds[i];
    Spart[ns * 16 + b] = s;
  }
}

__global__ __launch_bounds__(256) void treduce_kernel(const float* __restrict__ tpart,
                                                      const float* __restrict__ Spart,
                                                      float* __restrict__ tb,
                                                      float* __restrict__ S) {
  int b = blockIdx.x, e = threadIdx.x;
  float s = 0.f;
  for (int ns = 0; ns < kNS; ++ns) s += tpart[((long)ns * 16 + b) * 256 + e];
  tb[b * 256 + e] = s;
  if (e == 0) {
    float ss = 0.f;
    for (int ns = 0; ns < kNS; ++ns) ss += Spart[ns * 16 + b];
    S[b] = ss;
  }
}

__global__ __launch_bounds__(256) void gvec_kernel(const float* __restrict__ wq,
                                                   const float* __restrict__ bq,
                                                   const float* __restrict__ tb,
                                                   const float* __restrict__ S,
                                                   float* __restrict__ G) {
  int i = blockIdx.x * 4 + (threadIdx.x >> 6);
  int b = i >> 11, d = i & 2047;
  int lane = threadIdx.x & 63;
  float4 w4 = *(const float4*)(wq + (long)d * 256 + lane * 4);
  const float* tv = tb + b * 256 + lane * 4;
  float acc = w4.x * tv[0] + w4.y * tv[1] + w4.z * tv[2] + w4.w * tv[3];
#pragma unroll
  for (int o = 32; o >= 1; o >>= 1) acc += __shfl_xor(acc, o);
  if (lane == 0) G[i] = acc + bq[d] * S[b];
}

__global__ __launch_bounds__(256) void wfpg_kernel(const ushort_t* __restrict__ wfp,
                                                   const float* __restrict__ G,
                                                   ushort_t* __restrict__ wfpG) {
  long i = ((long)blockIdx.x * 256 + threadIdx.x) * 8;
  int b = (int)(i >> 19);
  long rem = i & 524287;
  int d = (int)(rem & 2047);
  uint4 raw = *(const uint4*)(wfp + rem);
  ushort_t* u = (ushort_t*)&raw;
  const float* g = G + b * 2048 + d;
#pragma unroll
  for (int j = 0; j < 8; ++j) u[j] = f2bf(bf2f(u[j]) * g[j]);
  *(uint4*)(wfpG + (long)b * 524288 + rem) = raw;
}

// ---------------- GEMM: 512 thr, dbuf, XCD-banded, 128x128, compile-time K ----------
// EPI 5: bf16 store (+b1?), LDS-coalesced
// EPI 3: bf16 gelu=erff(v+b1), LDS-coalesced
// EPI 4: f32 RMW: out += (row%kN==0 ? bf2f(auxb) : v+b1)
// EPI 10: stats partials (16 slices)
template <int EPI, int LDO, int KC>
__global__ __launch_bounds__(512) void gemm_kernel(
    const ushort_t* __restrict__ A, const ushort_t* __restrict__ W, int M,
    int NT, int MT, const float* __restrict__ b1, const ushort_t* __restrict__ auxb,
    void* __restrict__ out0, float* __restrict__ partbuf, long zA, long zRow) {
  __shared__ char smem[2 * 16384];
  const int t = threadIdx.x;
  const int wid = t >> 6, lane = t & 63;
  const int frow = lane & 15, kg = lane >> 4;
  const int wm = (wid >> 2) * 64;
  const int wn = (wid & 3) * 32;
  const int total = (int)gridDim.x;
  const int qq = total >> 3, rr = total & 7;
  const int xb = blockIdx.x & 7, ib = blockIdx.x >> 3;
  const int lg = (xb < rr ? xb * (qq + 1) : rr * (qq + 1) + (xb - rr) * qq) + ib;
  const int nt = lg % NT;
  const int mt = (lg / NT) % MT;
  const int z = lg / (NT * MT);
  const int n0 = nt * 128, m0 = mt * 128;
  A += (long)z * zA;

  const int srow = t >> 2;
  const int csw = ((t & 3) ^ ((t >> 3) & 3)) * 8;
  long arow = m0 + srow; if (arow > M - 1) arow = M - 1;
  const ushort_t* gA = A + arow * KC + csw;
  const ushort_t* gW = W + (long)(n0 + srow) * KC + csw;

  f32x4 acc[4][2];
#pragma unroll
  for (int mi = 0; mi < 4; ++mi)
#pragma unroll
    for (int ni = 0; ni < 2; ++ni) acc[mi][ni] = f32x4{0.f, 0.f, 0.f, 0.f};

  constexpr int KT = KC >> 5;
  auto stage = [&](int bi, int k0) {
    char* base = smem + bi * 16384 + (wid << 10);
    gload16(gA + k0, base);
    gload16(gW + k0, base + 8192);
  };
  stage(0, 0);
  __syncthreads();
#pragma unroll 2
  for (int kt = 0; kt < KT; ++kt) {
    const int cur = kt & 1;
    if (kt + 1 < KT) stage(cur ^ 1, (kt + 1) << 5);
    const char* bA = smem + cur * 16384;
    bf16x8 af[4], bw[2];
#pragma unroll
    for (int mi = 0; mi < 4; ++mi) {
      int r = wm + mi * 16 + frow;
      af[mi] = *(const bf16x8*)(bA + r * 64 + ((kg ^ ((r >> 1) & 3)) << 4));
    }
#pragma unroll
    for (int ni = 0; ni < 2; ++ni) {
      int r = wn + ni * 16 + frow;
      bw[ni] = *(const bf16x8*)(bA + 8192 + r * 64 + ((kg ^ ((r >> 1) & 3)) << 4));
    }
#pragma unroll
    for (int mi = 0; mi < 4; ++mi)
#pragma unroll
      for (int ni = 0; ni < 2; ++ni) acc[mi][ni] = mfma16(af[mi], bw[ni], acc[mi][ni]);
    __syncthreads();
  }

  if constexpr (EPI == 10) {
#pragma unroll
    for (int mi = 0; mi < 4; ++mi)
#pragma unroll
      for (int j = 0; j < 4; ++j) {
        const int gmi = m0 + wm + mi * 16 + kg * 4 + j;
        float rp = 0.f;
        if (gmi < M) {
#pragma unroll
          for (int ni = 0; ni < 2; ++ni) {
            const int gn = n0 + wn + ni * 16 + frow;
            rp += acc[mi][ni][j] * bf2f(A[(long)gmi * KC + (gn & 255)]);
          }
        }
#pragma unroll
        for (int off = 1; off <= 8; off <<= 1) rp += __shfl_xor(rp, off);
        if (frow == 0 && gmi < M)
          partbuf[(long)(nt * 4 + (wid & 3)) * M + gmi] = rp;
      }
    return;
  }

  if constexpr (EPI == 4) {
#pragma unroll
    for (int mi = 0; mi < 4; ++mi)
#pragma unroll
      for (int ni = 0; ni < 2; ++ni) {
        const int gn = n0 + wn + ni * 16 + frow;
#pragma unroll
        for (int j = 0; j < 4; ++j) {
          const int gmi = m0 + wm + mi * 16 + kg * 4 + j;
          if (gmi >= M) continue;
          const long idx = (long)gmi * LDO + gn;
          float v = acc[mi][ni][j] + b1[gn];
          const bool cls = (gmi % kN) == 0;
          ((float*)out0)[idx] += cls ? bf2f(auxb[idx]) : v;
        }
      }
    return;
  }

  // EPI 3/5: coalesced bf16 store via LDS
#pragma unroll
  for (int mi = 0; mi < 4; ++mi)
#pragma unroll
    for (int ni = 0; ni < 2; ++ni) {
      const int gn = n0 + wn + ni * 16 + frow;
      const int lcolb = (wn + ni * 16 + frow) * 2;
#pragma unroll
      for (int j = 0; j < 4; ++j) {
        const int lrow = wm + mi * 16 + kg * 4 + j;
        float v = acc[mi][ni][j];
        if (b1) v += b1[gn];
        if constexpr (EPI == 3)
          v = 0.5f * v * (1.0f + erff(v * 0.70710678118654752f));
        *(ushort_t*)(smem + lrow * 256 + (lcolb ^ ((lrow & 7) << 4))) = f2bf(v);
      }
    }
  __syncthreads();
#pragma unroll
  for (int p = 0; p < 4; ++p) {
    const int r = p * 32 + (t >> 4);
    const int cb = (t & 15) * 16;
    uint4 v = *(const uint4*)(smem + r * 256 + (cb ^ ((r & 7) << 4)));
    const int gmi = m0 + r;
    if (gmi < M)
      *(uint4*)((ushort_t*)out0 + ((long)z * zRow + gmi) * LDO + n0 + cb / 2) = v;
  }
}

// ---------------- prep3: {Mq, Mk, wfq} in one launch (12 blocks, z-select) ----------
__global__ __launch_bounds__(512) void prep3_kernel(
    const ushort_t* __restrict__ wqT, const ushort_t* __restrict__ wkT,
    const ushort_t* __restrict__ wf_bf, ushort_t* __restrict__ MqMk,
    ushort_t* __restrict__ wfq_bf) {
  __shared__ char smem[2 * 16384];
  const int t = threadIdx.x;
  const int wid = t >> 6, lane = t & 63;
  const int frow = lane & 15, kg = lane >> 4;
  const int wm = (wid >> 2) * 64;
  const int wn = (wid & 3) * 32;
  const int total = 12;
  const int qq = total >> 3, rr = total & 7;
  const int xb = blockIdx.x & 7, ib = blockIdx.x >> 3;
  const int lg = (xb < rr ? xb * (qq + 1) : rr * (qq + 1) + (xb - rr) * qq) + ib;
  const int nt = lg % 2, mt = (lg / 2) % 2, z = lg / 4;
  const int n0 = nt * 128, m0 = mt * 128;
  const ushort_t* A = z == 0 ? wqT : z == 1 ? wkT : wf_bf;
  const ushort_t* W = z == 1 ? wkT : wqT;
  ushort_t* out0 = z == 0 ? MqMk : z == 1 ? (MqMk + 65536) : wfq_bf;

  const int srow = t >> 2;
  const int csw = ((t & 3) ^ ((t >> 3) & 3)) * 8;
  const ushort_t* gA = A + (long)(m0 + srow) * 2048 + csw;
  const ushort_t* gW = W + (long)(n0 + srow) * 2048 + csw;

  f32x4 acc[4][2];
#pragma unroll
  for (int mi = 0; mi < 4; ++mi)
#pragma unroll
    for (int ni = 0; ni < 2; ++ni) acc[mi][ni] = f32x4{0.f, 0.f, 0.f, 0.f};

  auto stage = [&](int bi, int k0) {
    char* base = smem + bi * 16384 + (wid << 10);
    gload16(gA + k0, base);
    gload16(gW + k0, base + 8192);
  };
  stage(0, 0);
  __syncthreads();
#pragma unroll 2
  for (int kt = 0; kt < 64; ++kt) {
    const int cur = kt & 1;
    if (kt + 1 < 64) stage(cur ^ 1, (kt + 1) << 5);
    const char* bA = smem + cur * 16384;
    bf16x8 af[4], bw[2];
#pragma unroll
    for (int mi = 0; mi < 4; ++mi) {
      int r = wm + mi * 16 + frow;
      af[mi] = *(const bf16x8*)(bA + r * 64 + ((kg ^ ((r >> 1) & 3)) << 4));
    }
#pragma unroll
    for (int ni = 0; ni < 2; ++ni) {
      int r = wn + ni * 16 + frow;
      bw[ni] = *(const bf16x8*)(bA + 8192 + r * 64 + ((kg ^ ((r >> 1) & 3)) << 4));
    }
#pragma unroll
    for (int mi = 0; mi < 4; ++mi)
#pragma unroll
      for (int ni = 0; ni < 2; ++ni) acc[mi][ni] = mfma16(af[mi], bw[ni], acc[mi][ni]);
    __syncthreads();
  }
#pragma unroll
  for (int mi = 0; mi < 4; ++mi)
#pragma unroll
    for (int ni = 0; ni < 2; ++ni) {
      const int lcolb = (wn + ni * 16 + frow) * 2;
#pragma unroll
      for (int j = 0; j < 4; ++j) {
        const int lrow = wm + mi * 16 + kg * 4 + j;
        *(ushort_t*)(smem + lrow * 256 + (lcolb ^ ((lrow & 7) << 4))) =
            f2bf(acc[mi][ni][j]);
      }
    }
  __syncthreads();
#pragma unroll
  for (int p = 0; p < 4; ++p) {
    const int r = p * 32 + (t >> 4);
    const int cb = (t & 15) * 16;
    uint4 v = *(const uint4*)(smem + r * 256 + (cb ^ ((r & 7) << 4)));
    *(uint4*)(out0 + (long)(m0 + r) * 256 + n0 + cb / 2) = v;
  }
}

// ---------------- dual consumer: out = x + rs1*(xn@Wq^T+cfq)+cvec
//                  + rs2*(xn@Wc[z]^T+cb[z]).  Tile 128x128, 800 blocks. ----------------
__global__ __launch_bounds__(512) void dual_kernel(
    const ushort_t* __restrict__ xn, const ushort_t* __restrict__ Wq,
    const ushort_t* __restrict__ Wc, const float* __restrict__ cfq,
    const float* __restrict__ cb, const float* __restrict__ cvec,
    const float* __restrict__ rs1, const float* __restrict__ rs2,
    const float* __restrict__ xres, float* __restrict__ out) {
  constexpr int BUFB = 24576;
  __shared__ char smem[2 * BUFB];
  const int t = threadIdx.x;
  const int wid = t >> 6, lane = t & 63;
  const int frow = lane & 15, kg = lane >> 4;
  const int wm = (wid >> 2) * 64;
  const int wn = (wid & 3) * 32;
  const int total = (int)gridDim.x;  // 800
  const int qq = total >> 3, rr = total & 7;
  const int xb = blockIdx.x & 7, ib = blockIdx.x >> 3;
  const int lg = (xb < rr ? xb * (qq + 1) : rr * (qq + 1) + (xb - rr) * qq) + ib;
  const int nt = lg % 2;
  const int mt = (lg / 2) % 25;
  const int z = lg / 50;
  const int n0 = nt * 128, m0 = mt * 128;
  const ushort_t* A = xn + (long)z * kN * 256;
  const ushort_t* W2z = Wc + (long)z * 65536;

  const int srow = t >> 2;
  const int csw = ((t & 3) ^ ((t >> 3) & 3)) * 8;
  long arow = m0 + srow; if (arow > kN - 1) arow = kN - 1;
  const ushort_t* gA = A + arow * 256 + csw;
  const ushort_t* gW = Wq + (long)(n0 + srow) * 256 + csw;
  const ushort_t* gW2 = W2z + (long)(n0 + srow) * 256 + csw;

  f32x4 acc[4][2], accd[4][2];
#pragma unroll
  for (int mi = 0; mi < 4; ++mi)
#pragma unroll
    for (int ni = 0; ni < 2; ++ni) {
      acc[mi][ni] = f32x4{0.f, 0.f, 0.f, 0.f};
      accd[mi][ni] = f32x4{0.f, 0.f, 0.f, 0.f};
    }

  auto stage = [&](int bi, int k0) {
    char* base = smem + bi * BUFB + (wid << 10);
    gload16(gA + k0, base);
    gload16(gW + k0, base + 8192);
    gload16(gW2 + k0, base + 16384);
  };
  stage(0, 0);
  __syncthreads();
#pragma unroll 2
  for (int kt = 0; kt < 8; ++kt) {
    if (kt < 7) stage((kt + 1) & 1, (kt + 1) * 32);
    const char* bA = smem + (kt & 1) * BUFB;
    bf16x8 af[4], bw[2], bv[2];
#pragma unroll
    for (int mi = 0; mi < 4; ++mi) {
      int r = wm + mi * 16 + frow;
      af[mi] = *(const bf16x8*)(bA + r * 64 + ((kg ^ ((r >> 1) & 3)) << 4));
    }
#pragma unroll
    for (int ni = 0; ni < 2; ++ni) {
      int r = wn + ni * 16 + frow;
      int sw = (kg ^ ((r >> 1) & 3)) << 4;
      bw[ni] = *(const bf16x8*)(bA + 8192 + r * 64 + sw);
      bv[ni] = *(const bf16x8*)(bA + 16384 + r * 64 + sw);
    }
#pragma unroll
    for (int mi = 0; mi < 4; ++mi)
#pragma unroll
      for (int ni = 0; ni < 2; ++ni) {
        acc[mi][ni] = mfma16(af[mi], bw[ni], acc[mi][ni]);
        accd[mi][ni] = mfma16(af[mi], bv[ni], accd[mi][ni]);
      }
    __syncthreads();
  }

#pragma unroll
  for (int mi = 0; mi < 4; ++mi)
#pragma unroll
    for (int ni = 0; ni < 2; ++ni) {
      const int gn = n0 + wn + ni * 16 + frow;
#pragma unroll
      for (int j = 0; j < 4; ++j) {
        const int gmi = m0 + wm + mi * 16 + kg * 4 + j;
        if (gmi >= kN) continue;
        const long grow = (long)z * kN + gmi;
        const long idx = grow * 256 + gn;
        out[idx] = xres[idx] + rs1[grow] * (acc[mi][ni][j] + cfq[gn]) + cvec[gn] +
                   rs2[grow] * (accd[mi][ni][j] + cb[z * 256 + gn]);
      }
    }
}

// ---------------- host ----------------

extern "C" void kernel_launch(void* const* d_in, const int* in_sizes, int n_in,
                              void* d_out, int out_size, void* d_ws, size_t ws_size,
                              hipStream_t stream) {
  const float* x = (const float*)d_in[0];
  const float* n1w = (const float*)d_in[1];
  const float* n1b = (const float*)d_in[2];
  const float* wq = (const float*)d_in[3];
  const float* bq = (const float*)d_in[4];
  const float* wk = (const float*)d_in[5];
  const float* bk = (const float*)d_in[6];
  const float* wg = (const float*)d_in[7];
  const float* wp = (const float*)d_in[8];
  const float* bp = (const float*)d_in[9];
  const float* wf = (const float*)d_in[10];
  const float* bfv = (const float*)d_in[11];
  const float* n2w = (const float*)d_in[12];
  const float* n2b = (const float*)d_in[13];
  const float* w1 = (const float*)d_in[14];
  const float* b1 = (const float*)d_in[15];
  const float* w2 = (const float*)d_in[16];
  const float* b2 = (const float*)d_in[17];
  float* out = (float*)d_out;

  char* ws = (char*)d_ws;
  size_t off = 0;
  auto alloc = [&](size_t bytes) {
    size_t o = off;
    off += (bytes + 255) & ~(size_t)255;
    return o;
  };
  ushort_t* wqT = (ushort_t*)(ws + alloc((size_t)256 * 2048 * 2));
  ushort_t* wkT = (ushort_t*)(ws + alloc((size_t)256 * 2048 * 2));
  ushort_t* wpT = (ushort_t*)(ws + alloc((size_t)2048 * 2048 * 2));
  ushort_t* wf_bf = (ushort_t*)(ws + alloc((size_t)256 * 2048 * 2));
  ushort_t* w1_bf = (ushort_t*)(ws + alloc((size_t)1024 * 256 * 2));
  ushort_t* w2_bf = (ushort_t*)(ws + alloc((size_t)256 * 1024 * 2));
  ushort_t* MqMk = (ushort_t*)(ws + alloc((size_t)512 * 256 * 2));
  ushort_t* wfq_bf = (ushort_t*)(ws + alloc((size_t)256 * 256 * 2));
  ushort_t* wfp_bf = (ushort_t*)(ws + alloc((size_t)256 * 2048 * 2));
  ushort_t* wfpG = (ushort_t*)(ws + alloc((size_t)16 * 256 * 2048 * 2));
  ushort_t* Wc = (ushort_t*)(ws + alloc((size_t)16 * 256 * 256 * 2));
  float* uq = (float*)(ws + alloc(256 * 4));
  float* uk = (float*)(ws + alloc(256 * 4));
  float* vg = (float*)(ws + alloc(256 * 4));
  float* cfq = (float*)(ws + alloc(256 * 4));
  float* cvec = (float*)(ws + alloc(256 * 4));
  float* cb = (float*)(ws + alloc((size_t)16 * 256 * 4));
  float* scal = (float*)(ws + alloc(256));
  ushort_t* xn = (ushort_t*)(ws + alloc((size_t)kM * 256 * 2));  // xn, later xn2
  float* duq = (float*)(ws + alloc((size_t)kM * 4));
  float* duk = (float*)(ws + alloc((size_t)kM * 4));
  float* dvg = (float*)(ws + alloc((size_t)kM * 4));
  float* part = (float*)(ws + alloc((size_t)16 * kM * 4));
  float* rs_q = (float*)(ws + alloc((size_t)kM * 4));
  float* rs_k = (float*)(ws + alloc((size_t)kM * 4));
  float* Av = (float*)(ws + alloc((size_t)kM * 4));
  float* invA = (float*)(ws + alloc(64));
  float* tpart = (float*)(ws + alloc((size_t)kNS * 16 * 256 * 4));
  float* Spart = (float*)(ws + alloc((size_t)kNS * 16 * 4));
  float* tb = (float*)(ws + alloc((size_t)16 * 256 * 4));
  float* Sb = (float*)(ws + alloc(64));
  float* G = (float*)(ws + alloc((size_t)16 * 2048 * 4));
  ushort_t* hdn = (ushort_t*)(ws + alloc((size_t)kM * 1024 * 2));
  if (off > ws_size) return;

  // ---- weight prep (fused launches) ----
  transpose_cast_kernel<<<dim3(8, 64, 2), 256, 0, stream>>>(wq, wqT, wk, wkT, 2048, 256);
  transpose_cast_kernel<<<dim3(64, 64, 1), 256, 0, stream>>>(wp, wpT, wp, wpT, 2048, 2048);
  cast3_kernel<<<1024, 256, 0, stream>>>(wf, w1, w2, wf_bf, w1_bf, w2_bf);
  gemv5_kernel<<<dim3(64, 5), 256, 0, stream>>>(wqT, wkT, wf_bf, bq, bk, wg, bp, bfv,
                                                uq, uk, vg, cfq, cvec);
  scalars_kernel<<<1, 256, 0, stream>>>(bq, bk, wg, scal);
  prep3_kernel<<<12, 512, 0, stream>>>(wqT, wkT, wf_bf, MqMk, wfq_bf);
  gemm_kernel<5, 2048, 2048><<<32, 512, 0, stream>>>(wf_bf, wpT, 256, 16, 2, nullptr,
                                                     nullptr, wfp_bf, nullptr, 0, 0);

  // ---- LN1 (+dots) ----
  ln_kernel<<<(int)((kM + 3) / 4), 256, 0, stream>>>(x, n1w, n1b, xn, kM, uq, uk, vg,
                                                     duq, duk, dvg);
  // ---- stats GEMM (narrow, 16 slices) ----
  gemm_kernel<10, 256, 256><<<1572, 512, 0, stream>>>(xn, MqMk, (int)kM, 4, 393,
                                                      nullptr, nullptr, nullptr, part,
                                                      0, 0);
  reduce_rows_kernel<<<(int)((kM + 255) / 256), 256, 0, stream>>>(
      part, duq, duk, dvg, scal, rs_q, rs_k, Av);
  anorm_kernel<<<16, 256, 0, stream>>>(Av, invA);

  // ---- G = wq @ t + bq*S ----
  tvec_kernel<<<dim3(kNS, 16), 256, 0, stream>>>(xn, Av, rs_q, invA, tpart, Spart);
  treduce_kernel<<<16, 256, 0, stream>>>(tpart, Spart, tb, Sb);
  gvec_kernel<<<16 * 2048 / 4, 256, 0, stream>>>(wq, bq, tb, Sb, G);

  // ---- Wc[b] = (wfp . G[b]) @ wk ; cb[b] = (wfp . G[b]) @ bk ----
  wfpg_kernel<<<4096, 256, 0, stream>>>(wfp_bf, G, wfpG);
  gemv_kernel<<<1024, 256, 0, stream>>>(wfpG, bk, cb, 16 * 256, 2048);
  gemm_kernel<5, 256, 2048><<<64, 512, 0, stream>>>(wfpG, wkT, 256, 2, 2, nullptr,
                                                    nullptr, Wc, nullptr, 524288, 256);

  // ---- dual consumer: out = x + attn ----
  dual_kernel<<<800, 512, 0, stream>>>(xn, wfq_bf, Wc, cfq, cb, cvec, rs_q, rs_k,
                                       x, out);

  // ---- LN2 (separate pass): out -> xn2 (into xn buffer) ----
  ln_kernel<<<(int)((kM + 3) / 4), 256, 0, stream>>>(out, n2w, n2b, xn, kM, nullptr,
                                                     nullptr, nullptr, nullptr,
                                                     nullptr, nullptr);

  // ---- MLP: hdn = gelu(xn2@w1^T+b1); out += hdn@w2^T+b2 ----
  gemm_kernel<3, 1024, 256><<<3144, 512, 0, stream>>>(xn, w1_bf, (int)kM, 8, 393,
                                                      b1, nullptr, hdn, nullptr, 0, 0);
  gemm_kernel<4, 256, 1024><<<786, 512, 0, stream>>>(hdn, w2_bf, (int)kM, 2, 393,
                                                     b2, xn, out, nullptr, 0, 0);
}

// Round 14
// 372.965 us; speedup vs baseline: 1.0530x; 1.0530x over previous
//
#include <hip/hip_runtime.h>
#include <hip/hip_bf16.h>
#include <stdint.h>

typedef __bf16 bf16x8 __attribute__((ext_vector_type(8)));
typedef float f32x4 __attribute__((ext_vector_type(4)));
typedef unsigned short ushort_t;

static constexpr int kB = 16;
static constexpr int kN = 3137;           // 1 + 56*56
static constexpr long kM = (long)kB * kN; // 50192
static constexpr int kNS = 64;            // tvec n-split

__device__ __forceinline__ float bf2f(ushort_t u) {
  return __uint_as_float(((unsigned)u) << 16);
}
__device__ __forceinline__ ushort_t f2bf(float f) {
  __hip_bfloat16 h = __float2bfloat16(f);
  return *reinterpret_cast<ushort_t*>(&h);
}
__device__ __forceinline__ void gload16(const void* g, void* l) {
  __builtin_amdgcn_global_load_lds(
      (const __attribute__((address_space(1))) unsigned int*)g,
      (__attribute__((address_space(3))) unsigned int*)(uintptr_t)l,
      16, 0, 0);
}
__device__ __forceinline__ f32x4 mfma16(bf16x8 a, bf16x8 b, f32x4 c) {
  return __builtin_amdgcn_mfma_f32_16x16x32_bf16(a, b, c, 0, 0, 0);
}

// ---------------- prep kernels (launch-fused) ----------------

__global__ __launch_bounds__(256) void cast3_kernel(
    const float* __restrict__ wf, const float* __restrict__ w1,
    const float* __restrict__ w2, ushort_t* __restrict__ wf_bf,
    ushort_t* __restrict__ w1_bf, ushort_t* __restrict__ w2_bf) {
  long i = (long)blockIdx.x * 256 + threadIdx.x;  // over 262144 chunks
  const float* s;
  ushort_t* d;
  long o;
  if (i < 131072) { s = wf; d = wf_bf; o = i; }
  else if (i < 196608) { s = w1; d = w1_bf; o = i - 131072; }
  else { s = w2; d = w2_bf; o = i - 196608; }
  float4 v = *(const float4*)(s + o * 4);
  ushort4 u;
  u.x = f2bf(v.x); u.y = f2bf(v.y); u.z = f2bf(v.z); u.w = f2bf(v.w);
  *(ushort4*)(d + o * 4) = u;
}

__global__ __launch_bounds__(256) void transpose_cast_kernel(
    const float* __restrict__ srcA, ushort_t* __restrict__ dstA,
    const float* __restrict__ srcB, ushort_t* __restrict__ dstB, int R, int C) {
  __shared__ float tile[32][33];
  const float* src = (blockIdx.z == 0) ? srcA : srcB;
  ushort_t* dst = (blockIdx.z == 0) ? dstA : dstB;
  const int tx = blockIdx.x * 32, ty = blockIdx.y * 32;
  const int x = threadIdx.x & 31, y0 = threadIdx.x >> 5;
#pragma unroll
  for (int j = 0; j < 32; j += 8)
    tile[y0 + j][x] = src[(long)(ty + y0 + j) * C + tx + x];
  __syncthreads();
#pragma unroll
  for (int j = 0; j < 32; j += 8)
    dst[(long)(tx + y0 + j) * R + ty + x] = f2bf(tile[x][y0 + j]);
}

__global__ __launch_bounds__(256) void gemv5_kernel(
    const ushort_t* __restrict__ wqT, const ushort_t* __restrict__ wkT,
    const ushort_t* __restrict__ wf_bf, const float* __restrict__ bq,
    const float* __restrict__ bk, const float* __restrict__ wg,
    const float* __restrict__ bp, const float* __restrict__ bfv,
    float* __restrict__ uq, float* __restrict__ uk, float* __restrict__ vg,
    float* __restrict__ cfq, float* __restrict__ cvec) {
  const int job = blockIdx.y;
  const ushort_t* A = (job == 0 || job == 2) ? wqT : (job == 1 ? wkT : wf_bf);
  const float* v = (job == 0 || job == 3) ? bq : (job == 1 ? bk : (job == 2 ? wg : bp));
  float* out = job == 0 ? uq : job == 1 ? uk : job == 2 ? vg : job == 3 ? cfq : cvec;
  int row = blockIdx.x * 4 + (threadIdx.x >> 6);
  if (row >= 256) return;
  int lane = threadIdx.x & 63;
  float acc = 0.f;
  for (int k0 = lane * 8; k0 < 2048; k0 += 512) {
    uint4 raw = *(const uint4*)(A + (long)row * 2048 + k0);
    const ushort_t* u = (const ushort_t*)&raw;
#pragma unroll
    for (int j = 0; j < 8; ++j) acc += bf2f(u[j]) * v[k0 + j];
  }
#pragma unroll
  for (int o = 32; o >= 1; o >>= 1) acc += __shfl_xor(acc, o);
  if (lane == 0) out[row] = (job == 4 ? bfv[row] : 0.f) + acc;
}

__global__ __launch_bounds__(256) void gemv_kernel(const ushort_t* __restrict__ A,
                                                   const float* __restrict__ v,
                                                   float* __restrict__ out, int rows,
                                                   int K) {
  int row = blockIdx.x * 4 + (threadIdx.x >> 6);
  if (row >= rows) return;
  int lane = threadIdx.x & 63;
  float acc = 0.f;
  for (int k0 = lane * 8; k0 < K; k0 += 512) {
    uint4 raw = *(const uint4*)(A + (long)row * K + k0);
    const ushort_t* u = (const ushort_t*)&raw;
#pragma unroll
    for (int j = 0; j < 8; ++j) acc += bf2f(u[j]) * v[k0 + j];
  }
#pragma unroll
  for (int o = 32; o >= 1; o >>= 1) acc += __shfl_xor(acc, o);
  if (lane == 0) out[row] = acc;
}

__global__ __launch_bounds__(256) void scalars_kernel(const float* __restrict__ bq,
                                                      const float* __restrict__ bk,
                                                      const float* __restrict__ wg,
                                                      float* __restrict__ scal) {
  __shared__ float red[3][4];
  float s0 = 0, s1 = 0, s2 = 0;
  for (int i = threadIdx.x; i < 2048; i += 256) {
    s0 += bq[i] * bq[i];
    s1 += bk[i] * bk[i];
    s2 += bq[i] * wg[i];
  }
#pragma unroll
  for (int o = 32; o >= 1; o >>= 1) {
    s0 += __shfl_xor(s0, o); s1 += __shfl_xor(s1, o); s2 += __shfl_xor(s2, o);
  }
  int w = threadIdx.x >> 6;
  if ((threadIdx.x & 63) == 0) { red[0][w] = s0; red[1][w] = s1; red[2][w] = s2; }
  __syncthreads();
  if (threadIdx.x < 3)
    scal[threadIdx.x] = red[threadIdx.x][0] + red[threadIdx.x][1] +
                        red[threadIdx.x][2] + red[threadIdx.x][3];
}

__global__ __launch_bounds__(256) void ln_kernel(
    const float* __restrict__ x, const float* __restrict__ gw,
    const float* __restrict__ gb, ushort_t* __restrict__ out, long M,
    const float* __restrict__ uqv, const float* __restrict__ ukv,
    const float* __restrict__ vgv, float* __restrict__ duq,
    float* __restrict__ duk, float* __restrict__ dvg) {
  long row = (long)blockIdx.x * 4 + (threadIdx.x >> 6);
  if (row >= M) return;
  int lane = threadIdx.x & 63;
  float4 v = *(const float4*)(x + row * 256 + lane * 4);
  float s = v.x + v.y + v.z + v.w;
  float s2 = v.x * v.x + v.y * v.y + v.z * v.z + v.w * v.w;
#pragma unroll
  for (int o = 32; o >= 1; o >>= 1) {
    s += __shfl_xor(s, o);
    s2 += __shfl_xor(s2, o);
  }
  float mu = s * (1.f / 256.f);
  float var = fmaxf(s2 * (1.f / 256.f) - mu * mu, 0.f);
  float rsd = rsqrtf(var + 1e-5f);
  float e[4];
  ushort4 o4;
  e[0] = bf2f(o4.x = f2bf((v.x - mu) * rsd * gw[lane * 4 + 0] + gb[lane * 4 + 0]));
  e[1] = bf2f(o4.y = f2bf((v.y - mu) * rsd * gw[lane * 4 + 1] + gb[lane * 4 + 1]));
  e[2] = bf2f(o4.z = f2bf((v.z - mu) * rsd * gw[lane * 4 + 2] + gb[lane * 4 + 2]));
  e[3] = bf2f(o4.w = f2bf((v.w - mu) * rsd * gw[lane * 4 + 3] + gb[lane * 4 + 3]));
  *(ushort4*)(out + row * 256 + lane * 4) = o4;
  if (duq) {
    int base = lane * 4;
    float a = e[0] * uqv[base] + e[1] * uqv[base + 1] + e[2] * uqv[base + 2] + e[3] * uqv[base + 3];
    float b = e[0] * ukv[base] + e[1] * ukv[base + 1] + e[2] * ukv[base + 2] + e[3] * ukv[base + 3];
    float c = e[0] * vgv[base] + e[1] * vgv[base + 1] + e[2] * vgv[base + 2] + e[3] * vgv[base + 3];
#pragma unroll
    for (int o = 32; o >= 1; o >>= 1) {
      a += __shfl_xor(a, o); b += __shfl_xor(b, o); c += __shfl_xor(c, o);
    }
    if (lane == 0) { duq[row] = a; duk[row] = b; dvg[row] = c; }
  }
}

__global__ __launch_bounds__(256) void reduce_rows_kernel(
    const float* __restrict__ part, const float* __restrict__ duq,
    const float* __restrict__ duk, const float* __restrict__ dvg,
    const float* __restrict__ scal, float* __restrict__ rs_q,
    float* __restrict__ rs_k, float* __restrict__ Av) {
  long i = (long)blockIdx.x * 256 + threadIdx.x;
  if (i >= kM) return;
  float sq = 0.f, sk = 0.f;
#pragma unroll
  for (int s = 0; s < 8; ++s) sq += part[(long)s * kM + i];
#pragma unroll
  for (int s = 8; s < 16; ++s) sk += part[(long)s * kM + i];
  sq += 2.f * duq[i] + scal[0];
  sk += 2.f * duk[i] + scal[1];
  float rq = 1.f / fmaxf(sqrtf(fmaxf(sq, 0.f)), 1e-12f);
  float rk = 1.f / fmaxf(sqrtf(fmaxf(sk, 0.f)), 1e-12f);
  rs_q[i] = rq;
  rs_k[i] = rk;
  Av[i] = rq * (dvg[i] + scal[2]) * 0.0625f;
}

__global__ __launch_bounds__(256) void anorm_kernel(const float* __restrict__ Av,
                                                    float* __restrict__ invA) {
  int b = blockIdx.x;
  __shared__ float red[4];
  float s = 0.f;
  for (int n = threadIdx.x; n < kN; n += 256) {
    float a = Av[(long)b * kN + n];
    s += a * a;
  }
#pragma unroll
  for (int o = 32; o >= 1; o >>= 1) s += __shfl_xor(s, o);
  if ((threadIdx.x & 63) == 0) red[threadIdx.x >> 6] = s;
  __syncthreads();
  if (threadIdx.x == 0)
    invA[b] = 1.f / fmaxf(sqrtf(red[0] + red[1] + red[2] + red[3]), 1e-12f);
}

__global__ __launch_bounds__(256) void tvec_kernel(const ushort_t* __restrict__ xn,
                                                   const float* __restrict__ Av,
                                                   const float* __restrict__ rs_q,
                                                   const float* __restrict__ invA,
                                                   float* __restrict__ tpart,
                                                   float* __restrict__ Spart) {
  const int ns = blockIdx.x, b = blockIdx.y;
  const int n0 = ns * 50;
  int cnt = kN - n0; if (cnt > 50) cnt = 50; if (cnt < 0) cnt = 0;
  __shared__ float c_lds[50];
  const int t = threadIdx.x;
  if (t < cnt) {
    long gi = (long)b * kN + n0 + t;
    c_lds[t] = invA[b] * Av[gi] * rs_q[gi];
  }
  __syncthreads();
  float acc = 0.f;
  const ushort_t* p = xn + ((long)b * kN + n0) * 256 + t;
  for (int i = 0; i < cnt; ++i, p += 256) acc += c_lds[i] * bf2f(*p);
  tpart[((long)ns * 16 + b) * 256 + t] = acc;
  if (t == 0) {
    float s = 0.f;
    for (int i = 0; i < cnt; ++i) s += c_lds[i];
    Spart[ns * 16 + b] = s;
  }
}

__global__ __launch_bounds__(256) void treduce_kernel(const float* __restrict__ tpart,
                                                      const float* __restrict__ Spart,
                                                      float* __restrict__ tb,
                                                      float* __restrict__ S) {
  int b = blockIdx.x, e = threadIdx.x;
  float s = 0.f;
  for (int ns = 0; ns < kNS; ++ns) s += tpart[((long)ns * 16 + b) * 256 + e];
  tb[b * 256 + e] = s;
  if (e == 0) {
    float ss = 0.f;
    for (int ns = 0; ns < kNS; ++ns) ss += Spart[ns * 16 + b];
    S[b] = ss;
  }
}

__global__ __launch_bounds__(256) void gvec_kernel(const float* __restrict__ wq,
                                                   const float* __restrict__ bq,
                                                   const float* __restrict__ tb,
                                                   const float* __restrict__ S,
                                                   float* __restrict__ G) {
  int i = blockIdx.x * 4 + (threadIdx.x >> 6);
  int b = i >> 11, d = i & 2047;
  int lane = threadIdx.x & 63;
  float4 w4 = *(const float4*)(wq + (long)d * 256 + lane * 4);
  const float* tv = tb + b * 256 + lane * 4;
  float acc = w4.x * tv[0] + w4.y * tv[1] + w4.z * tv[2] + w4.w * tv[3];
#pragma unroll
  for (int o = 32; o >= 1; o >>= 1) acc += __shfl_xor(acc, o);
  if (lane == 0) G[i] = acc + bq[d] * S[b];
}

__global__ __launch_bounds__(256) void wfpg_kernel(const ushort_t* __restrict__ wfp,
                                                   const float* __restrict__ G,
                                                   ushort_t* __restrict__ wfpG) {
  long i = ((long)blockIdx.x * 256 + threadIdx.x) * 8;
  int b = (int)(i >> 19);
  long rem = i & 524287;
  int d = (int)(rem & 2047);
  uint4 raw = *(const uint4*)(wfp + rem);
  ushort_t* u = (ushort_t*)&raw;
  const float* g = G + b * 2048 + d;
#pragma unroll
  for (int j = 0; j < 8; ++j) u[j] = f2bf(bf2f(u[j]) * g[j]);
  *(uint4*)(wfpG + (long)b * 524288 + rem) = raw;
}

// ---------------- GEMM v3: 512 thr, 3-buffer counted-vmcnt pipeline, 128x128 ----------
// One raw barrier per k-step; vmcnt never drained to 0 in the main loop (T4).
// EPI 5: bf16 store (+b1?), LDS-coalesced
// EPI 3: bf16 gelu=erff(v+b1), LDS-coalesced
// EPI 4: f32 RMW: out += (row%kN==0 ? bf2f(auxb) : v+b1)
// EPI 10: stats partials (16 slices)
template <int EPI, int LDO, int KC>
__global__ __launch_bounds__(512) void gemm_kernel(
    const ushort_t* __restrict__ A, const ushort_t* __restrict__ W, int M,
    int NT, int MT, const float* __restrict__ b1, const ushort_t* __restrict__ auxb,
    void* __restrict__ out0, float* __restrict__ partbuf, long zA, long zRow) {
  __shared__ char smem[3 * 16384];  // 48KB: 3 x (A 8K + B 8K)
  const int t = threadIdx.x;
  const int wid = t >> 6, lane = t & 63;
  const int frow = lane & 15, kg = lane >> 4;
  const int wm = (wid >> 2) * 64;
  const int wn = (wid & 3) * 32;
  const int total = (int)gridDim.x;
  const int qq = total >> 3, rr = total & 7;
  const int xb = blockIdx.x & 7, ib = blockIdx.x >> 3;
  const int lg = (xb < rr ? xb * (qq + 1) : rr * (qq + 1) + (xb - rr) * qq) + ib;
  const int nt = lg % NT;
  const int mt = (lg / NT) % MT;
  const int z = lg / (NT * MT);
  const int n0 = nt * 128, m0 = mt * 128;
  A += (long)z * zA;

  const int srow = t >> 2;
  const int csw = ((t & 3) ^ ((t >> 3) & 3)) * 8;
  long arow = m0 + srow; if (arow > M - 1) arow = M - 1;
  const ushort_t* gA = A + arow * KC + csw;
  const ushort_t* gW = W + (long)(n0 + srow) * KC + csw;

  f32x4 acc[4][2];
#pragma unroll
  for (int mi = 0; mi < 4; ++mi)
#pragma unroll
    for (int ni = 0; ni < 2; ++ni) acc[mi][ni] = f32x4{0.f, 0.f, 0.f, 0.f};

  constexpr int KT = KC >> 5;
  auto stage = [&](int ti, int buf) {
    char* base = smem + buf * 16384 + (wid << 10);
    const int k0 = ti << 5;
    gload16(gA + k0, base);
    gload16(gW + k0, base + 8192);
  };
  auto compute = [&](const char* bA) {
    bf16x8 af[4], bw[2];
#pragma unroll
    for (int mi = 0; mi < 4; ++mi) {
      int r = wm + mi * 16 + frow;
      af[mi] = *(const bf16x8*)(bA + r * 64 + ((kg ^ ((r >> 1) & 3)) << 4));
    }
#pragma unroll
    for (int ni = 0; ni < 2; ++ni) {
      int r = wn + ni * 16 + frow;
      bw[ni] = *(const bf16x8*)(bA + 8192 + r * 64 + ((kg ^ ((r >> 1) & 3)) << 4));
    }
#pragma unroll
    for (int mi = 0; mi < 4; ++mi)
#pragma unroll
      for (int ni = 0; ni < 2; ++ni) acc[mi][ni] = mfma16(af[mi], bw[ni], acc[mi][ni]);
  };

  stage(0, 0);
  stage(1, 1);
#pragma unroll 3
  for (int kt = 0; kt < KT - 1; ++kt) {
    // tile kt landed (2 loads of kt+1 may remain in flight)
    asm volatile("s_waitcnt vmcnt(2)" ::: "memory");
    __builtin_amdgcn_s_barrier();
    __builtin_amdgcn_sched_barrier(0);
    if (kt + 2 < KT) stage(kt + 2, (kt + 2) % 3);
    compute(smem + (kt % 3) * 16384);
  }
  asm volatile("s_waitcnt vmcnt(0)" ::: "memory");
  __builtin_amdgcn_s_barrier();
  __builtin_amdgcn_sched_barrier(0);
  compute(smem + ((KT - 1) % 3) * 16384);

  if constexpr (EPI == 10) {
#pragma unroll
    for (int mi = 0; mi < 4; ++mi)
#pragma unroll
      for (int j = 0; j < 4; ++j) {
        const int gmi = m0 + wm + mi * 16 + kg * 4 + j;
        float rp = 0.f;
        if (gmi < M) {
#pragma unroll
          for (int ni = 0; ni < 2; ++ni) {
            const int gn = n0 + wn + ni * 16 + frow;
            rp += acc[mi][ni][j] * bf2f(A[(long)gmi * KC + (gn & 255)]);
          }
        }
#pragma unroll
        for (int off = 1; off <= 8; off <<= 1) rp += __shfl_xor(rp, off);
        if (frow == 0 && gmi < M)
          partbuf[(long)(nt * 4 + (wid & 3)) * M + gmi] = rp;
      }
    return;
  }

  if constexpr (EPI == 4) {
#pragma unroll
    for (int mi = 0; mi < 4; ++mi)
#pragma unroll
      for (int ni = 0; ni < 2; ++ni) {
        const int gn = n0 + wn + ni * 16 + frow;
#pragma unroll
        for (int j = 0; j < 4; ++j) {
          const int gmi = m0 + wm + mi * 16 + kg * 4 + j;
          if (gmi >= M) continue;
          const long idx = (long)gmi * LDO + gn;
          float v = acc[mi][ni][j] + b1[gn];
          const bool cls = (gmi % kN) == 0;
          ((float*)out0)[idx] += cls ? bf2f(auxb[idx]) : v;
        }
      }
    return;
  }

  // EPI 3/5: coalesced bf16 store via LDS (reuses pipeline buffers)
  __syncthreads();  // all waves done reading the k-loop buffers
#pragma unroll
  for (int mi = 0; mi < 4; ++mi)
#pragma unroll
    for (int ni = 0; ni < 2; ++ni) {
      const int gn = n0 + wn + ni * 16 + frow;
      const int lcolb = (wn + ni * 16 + frow) * 2;
#pragma unroll
      for (int j = 0; j < 4; ++j) {
        const int lrow = wm + mi * 16 + kg * 4 + j;
        float v = acc[mi][ni][j];
        if (b1) v += b1[gn];
        if constexpr (EPI == 3)
          v = 0.5f * v * (1.0f + erff(v * 0.70710678118654752f));
        *(ushort_t*)(smem + lrow * 256 + (lcolb ^ ((lrow & 7) << 4))) = f2bf(v);
      }
    }
  __syncthreads();
#pragma unroll
  for (int p = 0; p < 4; ++p) {
    const int r = p * 32 + (t >> 4);
    const int cb = (t & 15) * 16;
    uint4 v = *(const uint4*)(smem + r * 256 + (cb ^ ((r & 7) << 4)));
    const int gmi = m0 + r;
    if (gmi < M)
      *(uint4*)((ushort_t*)out0 + ((long)z * zRow + gmi) * LDO + n0 + cb / 2) = v;
  }
}

// ---------------- prep3: {Mq, Mk, wfq} in one launch (12 blocks, z-select) ----------
__global__ __launch_bounds__(512) void prep3_kernel(
    const ushort_t* __restrict__ wqT, const ushort_t* __restrict__ wkT,
    const ushort_t* __restrict__ wf_bf, ushort_t* __restrict__ MqMk,
    ushort_t* __restrict__ wfq_bf) {
  __shared__ char smem[2 * 16384];
  const int t = threadIdx.x;
  const int wid = t >> 6, lane = t & 63;
  const int frow = lane & 15, kg = lane >> 4;
  const int wm = (wid >> 2) * 64;
  const int wn = (wid & 3) * 32;
  const int total = 12;
  const int qq = total >> 3, rr = total & 7;
  const int xb = blockIdx.x & 7, ib = blockIdx.x >> 3;
  const int lg = (xb < rr ? xb * (qq + 1) : rr * (qq + 1) + (xb - rr) * qq) + ib;
  const int nt = lg % 2, mt = (lg / 2) % 2, z = lg / 4;
  const int n0 = nt * 128, m0 = mt * 128;
  const ushort_t* A = z == 0 ? wqT : z == 1 ? wkT : wf_bf;
  const ushort_t* W = z == 1 ? wkT : wqT;
  ushort_t* out0 = z == 0 ? MqMk : z == 1 ? (MqMk + 65536) : wfq_bf;

  const int srow = t >> 2;
  const int csw = ((t & 3) ^ ((t >> 3) & 3)) * 8;
  const ushort_t* gA = A + (long)(m0 + srow) * 2048 + csw;
  const ushort_t* gW = W + (long)(n0 + srow) * 2048 + csw;

  f32x4 acc[4][2];
#pragma unroll
  for (int mi = 0; mi < 4; ++mi)
#pragma unroll
    for (int ni = 0; ni < 2; ++ni) acc[mi][ni] = f32x4{0.f, 0.f, 0.f, 0.f};

  auto stage = [&](int bi, int k0) {
    char* base = smem + bi * 16384 + (wid << 10);
    gload16(gA + k0, base);
    gload16(gW + k0, base + 8192);
  };
  stage(0, 0);
  __syncthreads();
#pragma unroll 2
  for (int kt = 0; kt < 64; ++kt) {
    const int cur = kt & 1;
    if (kt + 1 < 64) stage(cur ^ 1, (kt + 1) << 5);
    const char* bA = smem + cur * 16384;
    bf16x8 af[4], bw[2];
#pragma unroll
    for (int mi = 0; mi < 4; ++mi) {
      int r = wm + mi * 16 + frow;
      af[mi] = *(const bf16x8*)(bA + r * 64 + ((kg ^ ((r >> 1) & 3)) << 4));
    }
#pragma unroll
    for (int ni = 0; ni < 2; ++ni) {
      int r = wn + ni * 16 + frow;
      bw[ni] = *(const bf16x8*)(bA + 8192 + r * 64 + ((kg ^ ((r >> 1) & 3)) << 4));
    }
#pragma unroll
    for (int mi = 0; mi < 4; ++mi)
#pragma unroll
      for (int ni = 0; ni < 2; ++ni) acc[mi][ni] = mfma16(af[mi], bw[ni], acc[mi][ni]);
    __syncthreads();
  }
#pragma unroll
  for (int mi = 0; mi < 4; ++mi)
#pragma unroll
    for (int ni = 0; ni < 2; ++ni) {
      const int lcolb = (wn + ni * 16 + frow) * 2;
#pragma unroll
      for (int j = 0; j < 4; ++j) {
        const int lrow = wm + mi * 16 + kg * 4 + j;
        *(ushort_t*)(smem + lrow * 256 + (lcolb ^ ((lrow & 7) << 4))) =
            f2bf(acc[mi][ni][j]);
      }
    }
  __syncthreads();
#pragma unroll
  for (int p = 0; p < 4; ++p) {
    const int r = p * 32 + (t >> 4);
    const int cb = (t & 15) * 16;
    uint4 v = *(const uint4*)(smem + r * 256 + (cb ^ ((r & 7) << 4)));
    *(uint4*)(out0 + (long)(m0 + r) * 256 + n0 + cb / 2) = v;
  }
}

// ---------------- dual consumer: out = x + rs1*(xn@Wq^T+cfq)+cvec
//                  + rs2*(xn@Wc[z]^T+cb[z]).  Tile 128x128, 800 blocks. ----------------
__global__ __launch_bounds__(512) void dual_kernel(
    const ushort_t* __restrict__ xn, const ushort_t* __restrict__ Wq,
    const ushort_t* __restrict__ Wc, const float* __restrict__ cfq,
    const float* __restrict__ cb, const float* __restrict__ cvec,
    const float* __restrict__ rs1, const float* __restrict__ rs2,
    const float* __restrict__ xres, float* __restrict__ out) {
  constexpr int BUFB = 24576;
  __shared__ char smem[2 * BUFB];
  const int t = threadIdx.x;
  const int wid = t >> 6, lane = t & 63;
  const int frow = lane & 15, kg = lane >> 4;
  const int wm = (wid >> 2) * 64;
  const int wn = (wid & 3) * 32;
  const int total = (int)gridDim.x;  // 800
  const int qq = total >> 3, rr = total & 7;
  const int xb = blockIdx.x & 7, ib = blockIdx.x >> 3;
  const int lg = (xb < rr ? xb * (qq + 1) : rr * (qq + 1) + (xb - rr) * qq) + ib;
  const int nt = lg % 2;
  const int mt = (lg / 2) % 25;
  const int z = lg / 50;
  const int n0 = nt * 128, m0 = mt * 128;
  const ushort_t* A = xn + (long)z * kN * 256;
  const ushort_t* W2z = Wc + (long)z * 65536;

  const int srow = t >> 2;
  const int csw = ((t & 3) ^ ((t >> 3) & 3)) * 8;
  long arow = m0 + srow; if (arow > kN - 1) arow = kN - 1;
  const ushort_t* gA = A + arow * 256 + csw;
  const ushort_t* gW = Wq + (long)(n0 + srow) * 256 + csw;
  const ushort_t* gW2 = W2z + (long)(n0 + srow) * 256 + csw;

  f32x4 acc[4][2], accd[4][2];
#pragma unroll
  for (int mi = 0; mi < 4; ++mi)
#pragma unroll
    for (int ni = 0; ni < 2; ++ni) {
      acc[mi][ni] = f32x4{0.f, 0.f, 0.f, 0.f};
      accd[mi][ni] = f32x4{0.f, 0.f, 0.f, 0.f};
    }

  auto stage = [&](int bi, int k0) {
    char* base = smem + bi * BUFB + (wid << 10);
    gload16(gA + k0, base);
    gload16(gW + k0, base + 8192);
    gload16(gW2 + k0, base + 16384);
  };
  stage(0, 0);
  __syncthreads();
#pragma unroll 2
  for (int kt = 0; kt < 8; ++kt) {
    if (kt < 7) stage((kt + 1) & 1, (kt + 1) * 32);
    const char* bA = smem + (kt & 1) * BUFB;
    bf16x8 af[4], bw[2], bv[2];
#pragma unroll
    for (int mi = 0; mi < 4; ++mi) {
      int r = wm + mi * 16 + frow;
      af[mi] = *(const bf16x8*)(bA + r * 64 + ((kg ^ ((r >> 1) & 3)) << 4));
    }
#pragma unroll
    for (int ni = 0; ni < 2; ++ni) {
      int r = wn + ni * 16 + frow;
      int sw = (kg ^ ((r >> 1) & 3)) << 4;
      bw[ni] = *(const bf16x8*)(bA + 8192 + r * 64 + sw);
      bv[ni] = *(const bf16x8*)(bA + 16384 + r * 64 + sw);
    }
#pragma unroll
    for (int mi = 0; mi < 4; ++mi)
#pragma unroll
      for (int ni = 0; ni < 2; ++ni) {
        acc[mi][ni] = mfma16(af[mi], bw[ni], acc[mi][ni]);
        accd[mi][ni] = mfma16(af[mi], bv[ni], accd[mi][ni]);
      }
    __syncthreads();
  }

#pragma unroll
  for (int mi = 0; mi < 4; ++mi)
#pragma unroll
    for (int ni = 0; ni < 2; ++ni) {
      const int gn = n0 + wn + ni * 16 + frow;
#pragma unroll
      for (int j = 0; j < 4; ++j) {
        const int gmi = m0 + wm + mi * 16 + kg * 4 + j;
        if (gmi >= kN) continue;
        const long grow = (long)z * kN + gmi;
        const long idx = grow * 256 + gn;
        out[idx] = xres[idx] + rs1[grow] * (acc[mi][ni][j] + cfq[gn]) + cvec[gn] +
                   rs2[grow] * (accd[mi][ni][j] + cb[z * 256 + gn]);
      }
    }
}

// ---------------- host ----------------

extern "C" void kernel_launch(void* const* d_in, const int* in_sizes, int n_in,
                              void* d_out, int out_size, void* d_ws, size_t ws_size,
                              hipStream_t stream) {
  const float* x = (const float*)d_in[0];
  const float* n1w = (const float*)d_in[1];
  const float* n1b = (const float*)d_in[2];
  const float* wq = (const float*)d_in[3];
  const float* bq = (const float*)d_in[4];
  const float* wk = (const float*)d_in[5];
  const float* bk = (const float*)d_in[6];
  const float* wg = (const float*)d_in[7];
  const float* wp = (const float*)d_in[8];
  const float* bp = (const float*)d_in[9];
  const float* wf = (const float*)d_in[10];
  const float* bfv = (const float*)d_in[11];
  const float* n2w = (const float*)d_in[12];
  const float* n2b = (const float*)d_in[13];
  const float* w1 = (const float*)d_in[14];
  const float* b1 = (const float*)d_in[15];
  const float* w2 = (const float*)d_in[16];
  const float* b2 = (const float*)d_in[17];
  float* out = (float*)d_out;

  char* ws = (char*)d_ws;
  size_t off = 0;
  auto alloc = [&](size_t bytes) {
    size_t o = off;
    off += (bytes + 255) & ~(size_t)255;
    return o;
  };
  ushort_t* wqT = (ushort_t*)(ws + alloc((size_t)256 * 2048 * 2));
  ushort_t* wkT = (ushort_t*)(ws + alloc((size_t)256 * 2048 * 2));
  ushort_t* wpT = (ushort_t*)(ws + alloc((size_t)2048 * 2048 * 2));
  ushort_t* wf_bf = (ushort_t*)(ws + alloc((size_t)256 * 2048 * 2));
  ushort_t* w1_bf = (ushort_t*)(ws + alloc((size_t)1024 * 256 * 2));
  ushort_t* w2_bf = (ushort_t*)(ws + alloc((size_t)256 * 1024 * 2));
  ushort_t* MqMk = (ushort_t*)(ws + alloc((size_t)512 * 256 * 2));
  ushort_t* wfq_bf = (ushort_t*)(ws + alloc((size_t)256 * 256 * 2));
  ushort_t* wfp_bf = (ushort_t*)(ws + alloc((size_t)256 * 2048 * 2));
  ushort_t* wfpG = (ushort_t*)(ws + alloc((size_t)16 * 256 * 2048 * 2));
  ushort_t* Wc = (ushort_t*)(ws + alloc((size_t)16 * 256 * 256 * 2));
  float* uq = (float*)(ws + alloc(256 * 4));
  float* uk = (float*)(ws + alloc(256 * 4));
  float* vg = (float*)(ws + alloc(256 * 4));
  float* cfq = (float*)(ws + alloc(256 * 4));
  float* cvec = (float*)(ws + alloc(256 * 4));
  float* cb = (float*)(ws + alloc((size_t)16 * 256 * 4));
  float* scal = (float*)(ws + alloc(256));
  ushort_t* xn = (ushort_t*)(ws + alloc((size_t)kM * 256 * 2));  // xn, later xn2
  float* duq = (float*)(ws + alloc((size_t)kM * 4));
  float* duk = (float*)(ws + alloc((size_t)kM * 4));
  float* dvg = (float*)(ws + alloc((size_t)kM * 4));
  float* part = (float*)(ws + alloc((size_t)16 * kM * 4));
  float* rs_q = (float*)(ws + alloc((size_t)kM * 4));
  float* rs_k = (float*)(ws + alloc((size_t)kM * 4));
  float* Av = (float*)(ws + alloc((size_t)kM * 4));
  float* invA = (float*)(ws + alloc(64));
  float* tpart = (float*)(ws + alloc((size_t)kNS * 16 * 256 * 4));
  float* Spart = (float*)(ws + alloc((size_t)kNS * 16 * 4));
  float* tb = (float*)(ws + alloc((size_t)16 * 256 * 4));
  float* Sb = (float*)(ws + alloc(64));
  float* G = (float*)(ws + alloc((size_t)16 * 2048 * 4));
  ushort_t* hdn = (ushort_t*)(ws + alloc((size_t)kM * 1024 * 2));
  if (off > ws_size) return;

  // ---- weight prep (fused launches) ----
  transpose_cast_kernel<<<dim3(8, 64, 2), 256, 0, stream>>>(wq, wqT, wk, wkT, 2048, 256);
  transpose_cast_kernel<<<dim3(64, 64, 1), 256, 0, stream>>>(wp, wpT, wp, wpT, 2048, 2048);
  cast3_kernel<<<1024, 256, 0, stream>>>(wf, w1, w2, wf_bf, w1_bf, w2_bf);
  gemv5_kernel<<<dim3(64, 5), 256, 0, stream>>>(wqT, wkT, wf_bf, bq, bk, wg, bp, bfv,
                                                uq, uk, vg, cfq, cvec);
  scalars_kernel<<<1, 256, 0, stream>>>(bq, bk, wg, scal);
  prep3_kernel<<<12, 512, 0, stream>>>(wqT, wkT, wf_bf, MqMk, wfq_bf);
  gemm_kernel<5, 2048, 2048><<<32, 512, 0, stream>>>(wf_bf, wpT, 256, 16, 2, nullptr,
                                                     nullptr, wfp_bf, nullptr, 0, 0);

  // ---- LN1 (+dots) ----
  ln_kernel<<<(int)((kM + 3) / 4), 256, 0, stream>>>(x, n1w, n1b, xn, kM, uq, uk, vg,
                                                     duq, duk, dvg);
  // ---- stats GEMM (narrow, 16 slices) ----
  gemm_kernel<10, 256, 256><<<1572, 512, 0, stream>>>(xn, MqMk, (int)kM, 4, 393,
                                                      nullptr, nullptr, nullptr, part,
                                                      0, 0);
  reduce_rows_kernel<<<(int)((kM + 255) / 256), 256, 0, stream>>>(
      part, duq, duk, dvg, scal, rs_q, rs_k, Av);
  anorm_kernel<<<16, 256, 0, stream>>>(Av, invA);

  // ---- G = wq @ t + bq*S ----
  tvec_kernel<<<dim3(kNS, 16), 256, 0, stream>>>(xn, Av, rs_q, invA, tpart, Spart);
  treduce_kernel<<<16, 256, 0, stream>>>(tpart, Spart, tb, Sb);
  gvec_kernel<<<16 * 2048 / 4, 256, 0, stream>>>(wq, bq, tb, Sb, G);

  // ---- Wc[b] = (wfp . G[b]) @ wk ; cb[b] = (wfp . G[b]) @ bk ----
  wfpg_kernel<<<4096, 256, 0, stream>>>(wfp_bf, G, wfpG);
  gemv_kernel<<<1024, 256, 0, stream>>>(wfpG, bk, cb, 16 * 256, 2048);
  gemm_kernel<5, 256, 2048><<<64, 512, 0, stream>>>(wfpG, wkT, 256, 2, 2, nullptr,
                                                    nullptr, Wc, nullptr, 524288, 256);

  // ---- dual consumer: out = x + attn ----
  dual_kernel<<<800, 512, 0, stream>>>(xn, wfq_bf, Wc, cfq, cb, cvec, rs_q, rs_k,
                                       x, out);

  // ---- LN2 (separate pass): out -> xn2 (into xn buffer) ----
  ln_kernel<<<(int)((kM + 3) / 4), 256, 0, stream>>>(out, n2w, n2b, xn, kM, nullptr,
                                                     nullptr, nullptr, nullptr,
                                                     nullptr, nullptr);

  // ---- MLP: hdn = gelu(xn2@w1^T+b1); out += hdn@w2^T+b2 ----
  gemm_kernel<3, 1024, 256><<<3144, 512, 0, stream>>>(xn, w1_bf, (int)kM, 8, 393,
                                                      b1, nullptr, hdn, nullptr, 0, 0);
  gemm_kernel<4, 256, 1024><<<786, 512, 0, stream>>>(hdn, w2_bf, (int)kM, 2, 393,
                                                     b2, xn, out, nullptr, 0, 0);
}

// Round 15
// 372.863 us; speedup vs baseline: 1.0533x; 1.0003x over previous
//
#include <hip/hip_runtime.h>
#include <hip/hip_bf16.h>
#include <stdint.h>

typedef __bf16 bf16x8 __attribute__((ext_vector_type(8)));
typedef float f32x4 __attribute__((ext_vector_type(4)));
typedef unsigned short ushort_t;

static constexpr int kB = 16;
static constexpr int kN = 3137;           // 1 + 56*56
static constexpr long kM = (long)kB * kN; // 50192
static constexpr int kNS = 64;            // tvec n-split

__device__ __forceinline__ float bf2f(ushort_t u) {
  return __uint_as_float(((unsigned)u) << 16);
}
__device__ __forceinline__ ushort_t f2bf(float f) {
  __hip_bfloat16 h = __float2bfloat16(f);
  return *reinterpret_cast<ushort_t*>(&h);
}
__device__ __forceinline__ void gload16(const void* g, void* l) {
  __builtin_amdgcn_global_load_lds(
      (const __attribute__((address_space(1))) unsigned int*)g,
      (__attribute__((address_space(3))) unsigned int*)(uintptr_t)l,
      16, 0, 0);
}
__device__ __forceinline__ f32x4 mfma16(bf16x8 a, bf16x8 b, f32x4 c) {
  return __builtin_amdgcn_mfma_f32_16x16x32_bf16(a, b, c, 0, 0, 0);
}

// ---------------- prep kernels (launch-fused) ----------------

__global__ __launch_bounds__(256) void cast3_kernel(
    const float* __restrict__ wf, const float* __restrict__ w1,
    const float* __restrict__ w2, ushort_t* __restrict__ wf_bf,
    ushort_t* __restrict__ w1_bf, ushort_t* __restrict__ w2_bf) {
  long i = (long)blockIdx.x * 256 + threadIdx.x;  // over 262144 chunks
  const float* s;
  ushort_t* d;
  long o;
  if (i < 131072) { s = wf; d = wf_bf; o = i; }
  else if (i < 196608) { s = w1; d = w1_bf; o = i - 131072; }
  else { s = w2; d = w2_bf; o = i - 196608; }
  float4 v = *(const float4*)(s + o * 4);
  ushort4 u;
  u.x = f2bf(v.x); u.y = f2bf(v.y); u.z = f2bf(v.z); u.w = f2bf(v.w);
  *(ushort4*)(d + o * 4) = u;
}

__global__ __launch_bounds__(256) void transpose_cast_kernel(
    const float* __restrict__ srcA, ushort_t* __restrict__ dstA,
    const float* __restrict__ srcB, ushort_t* __restrict__ dstB, int R, int C) {
  __shared__ float tile[32][33];
  const float* src = (blockIdx.z == 0) ? srcA : srcB;
  ushort_t* dst = (blockIdx.z == 0) ? dstA : dstB;
  const int tx = blockIdx.x * 32, ty = blockIdx.y * 32;
  const int x = threadIdx.x & 31, y0 = threadIdx.x >> 5;
#pragma unroll
  for (int j = 0; j < 32; j += 8)
    tile[y0 + j][x] = src[(long)(ty + y0 + j) * C + tx + x];
  __syncthreads();
#pragma unroll
  for (int j = 0; j < 32; j += 8)
    dst[(long)(tx + y0 + j) * R + ty + x] = f2bf(tile[x][y0 + j]);
}

__global__ __launch_bounds__(256) void gemv5_kernel(
    const ushort_t* __restrict__ wqT, const ushort_t* __restrict__ wkT,
    const ushort_t* __restrict__ wf_bf, const float* __restrict__ bq,
    const float* __restrict__ bk, const float* __restrict__ wg,
    const float* __restrict__ bp, const float* __restrict__ bfv,
    float* __restrict__ uq, float* __restrict__ uk, float* __restrict__ vg,
    float* __restrict__ cfq, float* __restrict__ cvec) {
  const int job = blockIdx.y;
  const ushort_t* A = (job == 0 || job == 2) ? wqT : (job == 1 ? wkT : wf_bf);
  const float* v = (job == 0 || job == 3) ? bq : (job == 1 ? bk : (job == 2 ? wg : bp));
  float* out = job == 0 ? uq : job == 1 ? uk : job == 2 ? vg : job == 3 ? cfq : cvec;
  int row = blockIdx.x * 4 + (threadIdx.x >> 6);
  if (row >= 256) return;
  int lane = threadIdx.x & 63;
  float acc = 0.f;
  for (int k0 = lane * 8; k0 < 2048; k0 += 512) {
    uint4 raw = *(const uint4*)(A + (long)row * 2048 + k0);
    const ushort_t* u = (const ushort_t*)&raw;
#pragma unroll
    for (int j = 0; j < 8; ++j) acc += bf2f(u[j]) * v[k0 + j];
  }
#pragma unroll
  for (int o = 32; o >= 1; o >>= 1) acc += __shfl_xor(acc, o);
  if (lane == 0) out[row] = (job == 4 ? bfv[row] : 0.f) + acc;
}

__global__ __launch_bounds__(256) void gemv_kernel(const ushort_t* __restrict__ A,
                                                   const float* __restrict__ v,
                                                   float* __restrict__ out, int rows,
                                                   int K) {
  int row = blockIdx.x * 4 + (threadIdx.x >> 6);
  if (row >= rows) return;
  int lane = threadIdx.x & 63;
  float acc = 0.f;
  for (int k0 = lane * 8; k0 < K; k0 += 512) {
    uint4 raw = *(const uint4*)(A + (long)row * K + k0);
    const ushort_t* u = (const ushort_t*)&raw;
#pragma unroll
    for (int j = 0; j < 8; ++j) acc += bf2f(u[j]) * v[k0 + j];
  }
#pragma unroll
  for (int o = 32; o >= 1; o >>= 1) acc += __shfl_xor(acc, o);
  if (lane == 0) out[row] = acc;
}

__global__ __launch_bounds__(256) void scalars_kernel(const float* __restrict__ bq,
                                                      const float* __restrict__ bk,
                                                      const float* __restrict__ wg,
                                                      float* __restrict__ scal) {
  __shared__ float red[3][4];
  float s0 = 0, s1 = 0, s2 = 0;
  for (int i = threadIdx.x; i < 2048; i += 256) {
    s0 += bq[i] * bq[i];
    s1 += bk[i] * bk[i];
    s2 += bq[i] * wg[i];
  }
#pragma unroll
  for (int o = 32; o >= 1; o >>= 1) {
    s0 += __shfl_xor(s0, o); s1 += __shfl_xor(s1, o); s2 += __shfl_xor(s2, o);
  }
  int w = threadIdx.x >> 6;
  if ((threadIdx.x & 63) == 0) { red[0][w] = s0; red[1][w] = s1; red[2][w] = s2; }
  __syncthreads();
  if (threadIdx.x < 3)
    scal[threadIdx.x] = red[threadIdx.x][0] + red[threadIdx.x][1] +
                        red[threadIdx.x][2] + red[threadIdx.x][3];
}

__global__ __launch_bounds__(256) void ln_kernel(
    const float* __restrict__ x, const float* __restrict__ gw,
    const float* __restrict__ gb, ushort_t* __restrict__ out, long M,
    const float* __restrict__ uqv, const float* __restrict__ ukv,
    const float* __restrict__ vgv, float* __restrict__ duq,
    float* __restrict__ duk, float* __restrict__ dvg) {
  long row = (long)blockIdx.x * 4 + (threadIdx.x >> 6);
  if (row >= M) return;
  int lane = threadIdx.x & 63;
  float4 v = *(const float4*)(x + row * 256 + lane * 4);
  float s = v.x + v.y + v.z + v.w;
  float s2 = v.x * v.x + v.y * v.y + v.z * v.z + v.w * v.w;
#pragma unroll
  for (int o = 32; o >= 1; o >>= 1) {
    s += __shfl_xor(s, o);
    s2 += __shfl_xor(s2, o);
  }
  float mu = s * (1.f / 256.f);
  float var = fmaxf(s2 * (1.f / 256.f) - mu * mu, 0.f);
  float rsd = rsqrtf(var + 1e-5f);
  float e[4];
  ushort4 o4;
  e[0] = bf2f(o4.x = f2bf((v.x - mu) * rsd * gw[lane * 4 + 0] + gb[lane * 4 + 0]));
  e[1] = bf2f(o4.y = f2bf((v.y - mu) * rsd * gw[lane * 4 + 1] + gb[lane * 4 + 1]));
  e[2] = bf2f(o4.z = f2bf((v.z - mu) * rsd * gw[lane * 4 + 2] + gb[lane * 4 + 2]));
  e[3] = bf2f(o4.w = f2bf((v.w - mu) * rsd * gw[lane * 4 + 3] + gb[lane * 4 + 3]));
  *(ushort4*)(out + row * 256 + lane * 4) = o4;
  if (duq) {
    int base = lane * 4;
    float a = e[0] * uqv[base] + e[1] * uqv[base + 1] + e[2] * uqv[base + 2] + e[3] * uqv[base + 3];
    float b = e[0] * ukv[base] + e[1] * ukv[base + 1] + e[2] * ukv[base + 2] + e[3] * ukv[base + 3];
    float c = e[0] * vgv[base] + e[1] * vgv[base + 1] + e[2] * vgv[base + 2] + e[3] * vgv[base + 3];
#pragma unroll
    for (int o = 32; o >= 1; o >>= 1) {
      a += __shfl_xor(a, o); b += __shfl_xor(b, o); c += __shfl_xor(c, o);
    }
    if (lane == 0) { duq[row] = a; duk[row] = b; dvg[row] = c; }
  }
}

__global__ __launch_bounds__(256) void reduce_rows_kernel(
    const float* __restrict__ part, const float* __restrict__ duq,
    const float* __restrict__ duk, const float* __restrict__ dvg,
    const float* __restrict__ scal, float* __restrict__ rs_q,
    float* __restrict__ rs_k, float* __restrict__ Av) {
  long i = (long)blockIdx.x * 256 + threadIdx.x;
  if (i >= kM) return;
  float sq = 0.f, sk = 0.f;
#pragma unroll
  for (int s = 0; s < 8; ++s) sq += part[(long)s * kM + i];
#pragma unroll
  for (int s = 8; s < 16; ++s) sk += part[(long)s * kM + i];
  sq += 2.f * duq[i] + scal[0];
  sk += 2.f * duk[i] + scal[1];
  float rq = 1.f / fmaxf(sqrtf(fmaxf(sq, 0.f)), 1e-12f);
  float rk = 1.f / fmaxf(sqrtf(fmaxf(sk, 0.f)), 1e-12f);
  rs_q[i] = rq;
  rs_k[i] = rk;
  Av[i] = rq * (dvg[i] + scal[2]) * 0.0625f;
}

__global__ __launch_bounds__(256) void anorm_kernel(const float* __restrict__ Av,
                                                    float* __restrict__ invA) {
  int b = blockIdx.x;
  __shared__ float red[4];
  float s = 0.f;
  for (int n = threadIdx.x; n < kN; n += 256) {
    float a = Av[(long)b * kN + n];
    s += a * a;
  }
#pragma unroll
  for (int o = 32; o >= 1; o >>= 1) s += __shfl_xor(s, o);
  if ((threadIdx.x & 63) == 0) red[threadIdx.x >> 6] = s;
  __syncthreads();
  if (threadIdx.x == 0)
    invA[b] = 1.f / fmaxf(sqrtf(red[0] + red[1] + red[2] + red[3]), 1e-12f);
}

__global__ __launch_bounds__(256) void tvec_kernel(const ushort_t* __restrict__ xn,
                                                   const float* __restrict__ Av,
                                                   const float* __restrict__ rs_q,
                                                   const float* __restrict__ invA,
                                                   float* __restrict__ tpart,
                                                   float* __restrict__ Spart) {
  const int ns = blockIdx.x, b = blockIdx.y;
  const int n0 = ns * 50;
  int cnt = kN - n0; if (cnt > 50) cnt = 50; if (cnt < 0) cnt = 0;
  __shared__ float c_lds[50];
  const int t = threadIdx.x;
  if (t < cnt) {
    long gi = (long)b * kN + n0 + t;
    c_lds[t] = invA[b] * Av[gi] * rs_q[gi];
  }
  __syncthreads();
  float acc = 0.f;
  const ushort_t* p = xn + ((long)b * kN + n0) * 256 + t;
  for (int i = 0; i < cnt; ++i, p += 256) acc += c_lds[i] * bf2f(*p);
  tpart[((long)ns * 16 + b) * 256 + t] = acc;
  if (t == 0) {
    float s = 0.f;
    for (int i = 0; i < cnt; ++i) s += c_lds[i];
    Spart[ns * 16 + b] = s;
  }
}

__global__ __launch_bounds__(256) void treduce_kernel(const float* __restrict__ tpart,
                                                      const float* __restrict__ Spart,
                                                      float* __restrict__ tb,
                                                      float* __restrict__ S) {
  int b = blockIdx.x, e = threadIdx.x;
  float s = 0.f;
  for (int ns = 0; ns < kNS; ++ns) s += tpart[((long)ns * 16 + b) * 256 + e];
  tb[b * 256 + e] = s;
  if (e == 0) {
    float ss = 0.f;
    for (int ns = 0; ns < kNS; ++ns) ss += Spart[ns * 16 + b];
    S[b] = ss;
  }
}

__global__ __launch_bounds__(256) void gvec_kernel(const float* __restrict__ wq,
                                                   const float* __restrict__ bq,
                                                   const float* __restrict__ tb,
                                                   const float* __restrict__ S,
                                                   float* __restrict__ G) {
  int i = blockIdx.x * 4 + (threadIdx.x >> 6);
  int b = i >> 11, d = i & 2047;
  int lane = threadIdx.x & 63;
  float4 w4 = *(const float4*)(wq + (long)d * 256 + lane * 4);
  const float* tv = tb + b * 256 + lane * 4;
  float acc = w4.x * tv[0] + w4.y * tv[1] + w4.z * tv[2] + w4.w * tv[3];
#pragma unroll
  for (int o = 32; o >= 1; o >>= 1) acc += __shfl_xor(acc, o);
  if (lane == 0) G[i] = acc + bq[d] * S[b];
}

__global__ __launch_bounds__(256) void wfpg_kernel(const ushort_t* __restrict__ wfp,
                                                   const float* __restrict__ G,
                                                   ushort_t* __restrict__ wfpG) {
  long i = ((long)blockIdx.x * 256 + threadIdx.x) * 8;
  int b = (int)(i >> 19);
  long rem = i & 524287;
  int d = (int)(rem & 2047);
  uint4 raw = *(const uint4*)(wfp + rem);
  ushort_t* u = (ushort_t*)&raw;
  const float* g = G + b * 2048 + d;
#pragma unroll
  for (int j = 0; j < 8; ++j) u[j] = f2bf(bf2f(u[j]) * g[j]);
  *(uint4*)(wfpG + (long)b * 524288 + rem) = raw;
}

// ---------------- GEMM v3: 512 thr, 3-buffer counted-vmcnt pipeline, 128x128 ----------
// One raw barrier per k-step; vmcnt never drained to 0 in the main loop (T4).
// T5: s_setprio(1) around the MFMA cluster.
// EPI 5: bf16 store (+b1?), LDS-coalesced
// EPI 3: bf16 gelu=erff(v+b1), LDS-coalesced
// EPI 4: f32 RMW: out += (row%kN==0 ? bf2f(auxb) : v+b1)
// EPI 10: stats partials (16 slices)
template <int EPI, int LDO, int KC>
__global__ __launch_bounds__(512) void gemm_kernel(
    const ushort_t* __restrict__ A, const ushort_t* __restrict__ W, int M,
    int NT, int MT, const float* __restrict__ b1, const ushort_t* __restrict__ auxb,
    void* __restrict__ out0, float* __restrict__ partbuf, long zA, long zRow) {
  __shared__ char smem[3 * 16384];  // 48KB: 3 x (A 8K + B 8K)
  const int t = threadIdx.x;
  const int wid = t >> 6, lane = t & 63;
  const int frow = lane & 15, kg = lane >> 4;
  const int wm = (wid >> 2) * 64;
  const int wn = (wid & 3) * 32;
  const int total = (int)gridDim.x;
  const int qq = total >> 3, rr = total & 7;
  const int xb = blockIdx.x & 7, ib = blockIdx.x >> 3;
  const int lg = (xb < rr ? xb * (qq + 1) : rr * (qq + 1) + (xb - rr) * qq) + ib;
  const int nt = lg % NT;
  const int mt = (lg / NT) % MT;
  const int z = lg / (NT * MT);
  const int n0 = nt * 128, m0 = mt * 128;
  A += (long)z * zA;

  const int srow = t >> 2;
  const int csw = ((t & 3) ^ ((t >> 3) & 3)) * 8;
  long arow = m0 + srow; if (arow > M - 1) arow = M - 1;
  const ushort_t* gA = A + arow * KC + csw;
  const ushort_t* gW = W + (long)(n0 + srow) * KC + csw;

  f32x4 acc[4][2];
#pragma unroll
  for (int mi = 0; mi < 4; ++mi)
#pragma unroll
    for (int ni = 0; ni < 2; ++ni) acc[mi][ni] = f32x4{0.f, 0.f, 0.f, 0.f};

  constexpr int KT = KC >> 5;
  auto stage = [&](int ti, int buf) {
    char* base = smem + buf * 16384 + (wid << 10);
    const int k0 = ti << 5;
    gload16(gA + k0, base);
    gload16(gW + k0, base + 8192);
  };
  auto compute = [&](const char* bA) {
    bf16x8 af[4], bw[2];
#pragma unroll
    for (int mi = 0; mi < 4; ++mi) {
      int r = wm + mi * 16 + frow;
      af[mi] = *(const bf16x8*)(bA + r * 64 + ((kg ^ ((r >> 1) & 3)) << 4));
    }
#pragma unroll
    for (int ni = 0; ni < 2; ++ni) {
      int r = wn + ni * 16 + frow;
      bw[ni] = *(const bf16x8*)(bA + 8192 + r * 64 + ((kg ^ ((r >> 1) & 3)) << 4));
    }
    __builtin_amdgcn_s_setprio(1);
#pragma unroll
    for (int mi = 0; mi < 4; ++mi)
#pragma unroll
      for (int ni = 0; ni < 2; ++ni) acc[mi][ni] = mfma16(af[mi], bw[ni], acc[mi][ni]);
    __builtin_amdgcn_s_setprio(0);
  };

  stage(0, 0);
  stage(1, 1);
#pragma unroll 3
  for (int kt = 0; kt < KT - 1; ++kt) {
    // tile kt landed (2 loads of kt+1 may remain in flight)
    asm volatile("s_waitcnt vmcnt(2)" ::: "memory");
    __builtin_amdgcn_s_barrier();
    __builtin_amdgcn_sched_barrier(0);
    if (kt + 2 < KT) stage(kt + 2, (kt + 2) % 3);
    compute(smem + (kt % 3) * 16384);
  }
  asm volatile("s_waitcnt vmcnt(0)" ::: "memory");
  __builtin_amdgcn_s_barrier();
  __builtin_amdgcn_sched_barrier(0);
  compute(smem + ((KT - 1) % 3) * 16384);

  if constexpr (EPI == 10) {
#pragma unroll
    for (int mi = 0; mi < 4; ++mi)
#pragma unroll
      for (int j = 0; j < 4; ++j) {
        const int gmi = m0 + wm + mi * 16 + kg * 4 + j;
        float rp = 0.f;
        if (gmi < M) {
#pragma unroll
          for (int ni = 0; ni < 2; ++ni) {
            const int gn = n0 + wn + ni * 16 + frow;
            rp += acc[mi][ni][j] * bf2f(A[(long)gmi * KC + (gn & 255)]);
          }
        }
#pragma unroll
        for (int off = 1; off <= 8; off <<= 1) rp += __shfl_xor(rp, off);
        if (frow == 0 && gmi < M)
          partbuf[(long)(nt * 4 + (wid & 3)) * M + gmi] = rp;
      }
    return;
  }

  if constexpr (EPI == 4) {
#pragma unroll
    for (int mi = 0; mi < 4; ++mi)
#pragma unroll
      for (int ni = 0; ni < 2; ++ni) {
        const int gn = n0 + wn + ni * 16 + frow;
#pragma unroll
        for (int j = 0; j < 4; ++j) {
          const int gmi = m0 + wm + mi * 16 + kg * 4 + j;
          if (gmi >= M) continue;
          const long idx = (long)gmi * LDO + gn;
          float v = acc[mi][ni][j] + b1[gn];
          const bool cls = (gmi % kN) == 0;
          ((float*)out0)[idx] += cls ? bf2f(auxb[idx]) : v;
        }
      }
    return;
  }

  // EPI 3/5: coalesced bf16 store via LDS (reuses pipeline buffers)
  __syncthreads();  // all waves done reading the k-loop buffers
#pragma unroll
  for (int mi = 0; mi < 4; ++mi)
#pragma unroll
    for (int ni = 0; ni < 2; ++ni) {
      const int gn = n0 + wn + ni * 16 + frow;
      const int lcolb = (wn + ni * 16 + frow) * 2;
#pragma unroll
      for (int j = 0; j < 4; ++j) {
        const int lrow = wm + mi * 16 + kg * 4 + j;
        float v = acc[mi][ni][j];
        if (b1) v += b1[gn];
        if constexpr (EPI == 3)
          v = 0.5f * v * (1.0f + erff(v * 0.70710678118654752f));
        *(ushort_t*)(smem + lrow * 256 + (lcolb ^ ((lrow & 7) << 4))) = f2bf(v);
      }
    }
  __syncthreads();
#pragma unroll
  for (int p = 0; p < 4; ++p) {
    const int r = p * 32 + (t >> 4);
    const int cb = (t & 15) * 16;
    uint4 v = *(const uint4*)(smem + r * 256 + (cb ^ ((r & 7) << 4)));
    const int gmi = m0 + r;
    if (gmi < M)
      *(uint4*)((ushort_t*)out0 + ((long)z * zRow + gmi) * LDO + n0 + cb / 2) = v;
  }
}

// ---------------- prep3: {Mq, Mk, wfq} in one launch (12 blocks, z-select) ----------
__global__ __launch_bounds__(512) void prep3_kernel(
    const ushort_t* __restrict__ wqT, const ushort_t* __restrict__ wkT,
    const ushort_t* __restrict__ wf_bf, ushort_t* __restrict__ MqMk,
    ushort_t* __restrict__ wfq_bf) {
  __shared__ char smem[2 * 16384];
  const int t = threadIdx.x;
  const int wid = t >> 6, lane = t & 63;
  const int frow = lane & 15, kg = lane >> 4;
  const int wm = (wid >> 2) * 64;
  const int wn = (wid & 3) * 32;
  const int total = 12;
  const int qq = total >> 3, rr = total & 7;
  const int xb = blockIdx.x & 7, ib = blockIdx.x >> 3;
  const int lg = (xb < rr ? xb * (qq + 1) : rr * (qq + 1) + (xb - rr) * qq) + ib;
  const int nt = lg % 2, mt = (lg / 2) % 2, z = lg / 4;
  const int n0 = nt * 128, m0 = mt * 128;
  const ushort_t* A = z == 0 ? wqT : z == 1 ? wkT : wf_bf;
  const ushort_t* W = z == 1 ? wkT : wqT;
  ushort_t* out0 = z == 0 ? MqMk : z == 1 ? (MqMk + 65536) : wfq_bf;

  const int srow = t >> 2;
  const int csw = ((t & 3) ^ ((t >> 3) & 3)) * 8;
  const ushort_t* gA = A + (long)(m0 + srow) * 2048 + csw;
  const ushort_t* gW = W + (long)(n0 + srow) * 2048 + csw;

  f32x4 acc[4][2];
#pragma unroll
  for (int mi = 0; mi < 4; ++mi)
#pragma unroll
    for (int ni = 0; ni < 2; ++ni) acc[mi][ni] = f32x4{0.f, 0.f, 0.f, 0.f};

  auto stage = [&](int bi, int k0) {
    char* base = smem + bi * 16384 + (wid << 10);
    gload16(gA + k0, base);
    gload16(gW + k0, base + 8192);
  };
  stage(0, 0);
  __syncthreads();
#pragma unroll 2
  for (int kt = 0; kt < 64; ++kt) {
    const int cur = kt & 1;
    if (kt + 1 < 64) stage(cur ^ 1, (kt + 1) << 5);
    const char* bA = smem + cur * 16384;
    bf16x8 af[4], bw[2];
#pragma unroll
    for (int mi = 0; mi < 4; ++mi) {
      int r = wm + mi * 16 + frow;
      af[mi] = *(const bf16x8*)(bA + r * 64 + ((kg ^ ((r >> 1) & 3)) << 4));
    }
#pragma unroll
    for (int ni = 0; ni < 2; ++ni) {
      int r = wn + ni * 16 + frow;
      bw[ni] = *(const bf16x8*)(bA + 8192 + r * 64 + ((kg ^ ((r >> 1) & 3)) << 4));
    }
#pragma unroll
    for (int mi = 0; mi < 4; ++mi)
#pragma unroll
      for (int ni = 0; ni < 2; ++ni) acc[mi][ni] = mfma16(af[mi], bw[ni], acc[mi][ni]);
    __syncthreads();
  }
#pragma unroll
  for (int mi = 0; mi < 4; ++mi)
#pragma unroll
    for (int ni = 0; ni < 2; ++ni) {
      const int lcolb = (wn + ni * 16 + frow) * 2;
#pragma unroll
      for (int j = 0; j < 4; ++j) {
        const int lrow = wm + mi * 16 + kg * 4 + j;
        *(ushort_t*)(smem + lrow * 256 + (lcolb ^ ((lrow & 7) << 4))) =
            f2bf(acc[mi][ni][j]);
      }
    }
  __syncthreads();
#pragma unroll
  for (int p = 0; p < 4; ++p) {
    const int r = p * 32 + (t >> 4);
    const int cb = (t & 15) * 16;
    uint4 v = *(const uint4*)(smem + r * 256 + (cb ^ ((r & 7) << 4)));
    *(uint4*)(out0 + (long)(m0 + r) * 256 + n0 + cb / 2) = v;
  }
}

// ---------------- dual consumer: out = x + rs1*(xn@Wq^T+cfq)+cvec
//                  + rs2*(xn@Wc[z]^T+cb[z]).  Tile 128x128, 800 blocks. ----------------
__global__ __launch_bounds__(512) void dual_kernel(
    const ushort_t* __restrict__ xn, const ushort_t* __restrict__ Wq,
    const ushort_t* __restrict__ Wc, const float* __restrict__ cfq,
    const float* __restrict__ cb, const float* __restrict__ cvec,
    const float* __restrict__ rs1, const float* __restrict__ rs2,
    const float* __restrict__ xres, float* __restrict__ out) {
  constexpr int BUFB = 24576;
  __shared__ char smem[2 * BUFB];
  const int t = threadIdx.x;
  const int wid = t >> 6, lane = t & 63;
  const int frow = lane & 15, kg = lane >> 4;
  const int wm = (wid >> 2) * 64;
  const int wn = (wid & 3) * 32;
  const int total = (int)gridDim.x;  // 800
  const int qq = total >> 3, rr = total & 7;
  const int xb = blockIdx.x & 7, ib = blockIdx.x >> 3;
  const int lg = (xb < rr ? xb * (qq + 1) : rr * (qq + 1) + (xb - rr) * qq) + ib;
  const int nt = lg % 2;
  const int mt = (lg / 2) % 25;
  const int z = lg / 50;
  const int n0 = nt * 128, m0 = mt * 128;
  const ushort_t* A = xn + (long)z * kN * 256;
  const ushort_t* W2z = Wc + (long)z * 65536;

  const int srow = t >> 2;
  const int csw = ((t & 3) ^ ((t >> 3) & 3)) * 8;
  long arow = m0 + srow; if (arow > kN - 1) arow = kN - 1;
  const ushort_t* gA = A + arow * 256 + csw;
  const ushort_t* gW = Wq + (long)(n0 + srow) * 256 + csw;
  const ushort_t* gW2 = W2z + (long)(n0 + srow) * 256 + csw;

  f32x4 acc[4][2], accd[4][2];
#pragma unroll
  for (int mi = 0; mi < 4; ++mi)
#pragma unroll
    for (int ni = 0; ni < 2; ++ni) {
      acc[mi][ni] = f32x4{0.f, 0.f, 0.f, 0.f};
      accd[mi][ni] = f32x4{0.f, 0.f, 0.f, 0.f};
    }

  auto stage = [&](int bi, int k0) {
    char* base = smem + bi * BUFB + (wid << 10);
    gload16(gA + k0, base);
    gload16(gW + k0, base + 8192);
    gload16(gW2 + k0, base + 16384);
  };
  stage(0, 0);
  __syncthreads();
#pragma unroll 2
  for (int kt = 0; kt < 8; ++kt) {
    if (kt < 7) stage((kt + 1) & 1, (kt + 1) * 32);
    const char* bA = smem + (kt & 1) * BUFB;
    bf16x8 af[4], bw[2], bv[2];
#pragma unroll
    for (int mi = 0; mi < 4; ++mi) {
      int r = wm + mi * 16 + frow;
      af[mi] = *(const bf16x8*)(bA + r * 64 + ((kg ^ ((r >> 1) & 3)) << 4));
    }
#pragma unroll
    for (int ni = 0; ni < 2; ++ni) {
      int r = wn + ni * 16 + frow;
      int sw = (kg ^ ((r >> 1) & 3)) << 4;
      bw[ni] = *(const bf16x8*)(bA + 8192 + r * 64 + sw);
      bv[ni] = *(const bf16x8*)(bA + 16384 + r * 64 + sw);
    }
    __builtin_amdgcn_s_setprio(1);
#pragma unroll
    for (int mi = 0; mi < 4; ++mi)
#pragma unroll
      for (int ni = 0; ni < 2; ++ni) {
        acc[mi][ni] = mfma16(af[mi], bw[ni], acc[mi][ni]);
        accd[mi][ni] = mfma16(af[mi], bv[ni], accd[mi][ni]);
      }
    __builtin_amdgcn_s_setprio(0);
    __syncthreads();
  }

#pragma unroll
  for (int mi = 0; mi < 4; ++mi)
#pragma unroll
    for (int ni = 0; ni < 2; ++ni) {
      const int gn = n0 + wn + ni * 16 + frow;
#pragma unroll
      for (int j = 0; j < 4; ++j) {
        const int gmi = m0 + wm + mi * 16 + kg * 4 + j;
        if (gmi >= kN) continue;
        const long grow = (long)z * kN + gmi;
        const long idx = grow * 256 + gn;
        out[idx] = xres[idx] + rs1[grow] * (acc[mi][ni][j] + cfq[gn]) + cvec[gn] +
                   rs2[grow] * (accd[mi][ni][j] + cb[z * 256 + gn]);
      }
    }
}

// ---------------- host ----------------

extern "C" void kernel_launch(void* const* d_in, const int* in_sizes, int n_in,
                              void* d_out, int out_size, void* d_ws, size_t ws_size,
                              hipStream_t stream) {
  const float* x = (const float*)d_in[0];
  const float* n1w = (const float*)d_in[1];
  const float* n1b = (const float*)d_in[2];
  const float* wq = (const float*)d_in[3];
  const float* bq = (const float*)d_in[4];
  const float* wk = (const float*)d_in[5];
  const float* bk = (const float*)d_in[6];
  const float* wg = (const float*)d_in[7];
  const float* wp = (const float*)d_in[8];
  const float* bp = (const float*)d_in[9];
  const float* wf = (const float*)d_in[10];
  const float* bfv = (const float*)d_in[11];
  const float* n2w = (const float*)d_in[12];
  const float* n2b = (const float*)d_in[13];
  const float* w1 = (const float*)d_in[14];
  const float* b1 = (const float*)d_in[15];
  const float* w2 = (const float*)d_in[16];
  const float* b2 = (const float*)d_in[17];
  float* out = (float*)d_out;

  char* ws = (char*)d_ws;
  size_t off = 0;
  auto alloc = [&](size_t bytes) {
    size_t o = off;
    off += (bytes + 255) & ~(size_t)255;
    return o;
  };
  ushort_t* wqT = (ushort_t*)(ws + alloc((size_t)256 * 2048 * 2));
  ushort_t* wkT = (ushort_t*)(ws + alloc((size_t)256 * 2048 * 2));
  ushort_t* wpT = (ushort_t*)(ws + alloc((size_t)2048 * 2048 * 2));
  ushort_t* wf_bf = (ushort_t*)(ws + alloc((size_t)256 * 2048 * 2));
  ushort_t* w1_bf = (ushort_t*)(ws + alloc((size_t)1024 * 256 * 2));
  ushort_t* w2_bf = (ushort_t*)(ws + alloc((size_t)256 * 1024 * 2));
  ushort_t* MqMk = (ushort_t*)(ws + alloc((size_t)512 * 256 * 2));
  ushort_t* wfq_bf = (ushort_t*)(ws + alloc((size_t)256 * 256 * 2));
  ushort_t* wfp_bf = (ushort_t*)(ws + alloc((size_t)256 * 2048 * 2));
  ushort_t* wfpG = (ushort_t*)(ws + alloc((size_t)16 * 256 * 2048 * 2));
  ushort_t* Wc = (ushort_t*)(ws + alloc((size_t)16 * 256 * 256 * 2));
  float* uq = (float*)(ws + alloc(256 * 4));
  float* uk = (float*)(ws + alloc(256 * 4));
  float* vg = (float*)(ws + alloc(256 * 4));
  float* cfq = (float*)(ws + alloc(256 * 4));
  float* cvec = (float*)(ws + alloc(256 * 4));
  float* cb = (float*)(ws + alloc((size_t)16 * 256 * 4));
  float* scal = (float*)(ws + alloc(256));
  ushort_t* xn = (ushort_t*)(ws + alloc((size_t)kM * 256 * 2));  // xn, later xn2
  float* duq = (float*)(ws + alloc((size_t)kM * 4));
  float* duk = (float*)(ws + alloc((size_t)kM * 4));
  float* dvg = (float*)(ws + alloc((size_t)kM * 4));
  float* part = (float*)(ws + alloc((size_t)16 * kM * 4));
  float* rs_q = (float*)(ws + alloc((size_t)kM * 4));
  float* rs_k = (float*)(ws + alloc((size_t)kM * 4));
  float* Av = (float*)(ws + alloc((size_t)kM * 4));
  float* invA = (float*)(ws + alloc(64));
  float* tpart = (float*)(ws + alloc((size_t)kNS * 16 * 256 * 4));
  float* Spart = (float*)(ws + alloc((size_t)kNS * 16 * 4));
  float* tb = (float*)(ws + alloc((size_t)16 * 256 * 4));
  float* Sb = (float*)(ws + alloc(64));
  float* G = (float*)(ws + alloc((size_t)16 * 2048 * 4));
  ushort_t* hdn = (ushort_t*)(ws + alloc((size_t)kM * 1024 * 2));
  if (off > ws_size) return;

  // ---- weight prep (fused launches) ----
  transpose_cast_kernel<<<dim3(8, 64, 2), 256, 0, stream>>>(wq, wqT, wk, wkT, 2048, 256);
  transpose_cast_kernel<<<dim3(64, 64, 1), 256, 0, stream>>>(wp, wpT, wp, wpT, 2048, 2048);
  cast3_kernel<<<1024, 256, 0, stream>>>(wf, w1, w2, wf_bf, w1_bf, w2_bf);
  gemv5_kernel<<<dim3(64, 5), 256, 0, stream>>>(wqT, wkT, wf_bf, bq, bk, wg, bp, bfv,
                                                uq, uk, vg, cfq, cvec);
  scalars_kernel<<<1, 256, 0, stream>>>(bq, bk, wg, scal);
  prep3_kernel<<<12, 512, 0, stream>>>(wqT, wkT, wf_bf, MqMk, wfq_bf);
  gemm_kernel<5, 2048, 2048><<<32, 512, 0, stream>>>(wf_bf, wpT, 256, 16, 2, nullptr,
                                                     nullptr, wfp_bf, nullptr, 0, 0);

  // ---- LN1 (+dots) ----
  ln_kernel<<<(int)((kM + 3) / 4), 256, 0, stream>>>(x, n1w, n1b, xn, kM, uq, uk, vg,
                                                     duq, duk, dvg);
  // ---- stats GEMM (narrow, 16 slices) ----
  gemm_kernel<10, 256, 256><<<1572, 512, 0, stream>>>(xn, MqMk, (int)kM, 4, 393,
                                                      nullptr, nullptr, nullptr, part,
                                                      0, 0);
  reduce_rows_kernel<<<(int)((kM + 255) / 256), 256, 0, stream>>>(
      part, duq, duk, dvg, scal, rs_q, rs_k, Av);
  anorm_kernel<<<16, 256, 0, stream>>>(Av, invA);

  // ---- G = wq @ t + bq*S ----
  tvec_kernel<<<dim3(kNS, 16), 256, 0, stream>>>(xn, Av, rs_q, invA, tpart, Spart);
  treduce_kernel<<<16, 256, 0, stream>>>(tpart, Spart, tb, Sb);
  gvec_kernel<<<16 * 2048 / 4, 256, 0, stream>>>(wq, bq, tb, Sb, G);

  // ---- Wc[b] = (wfp . G[b]) @ wk ; cb[b] = (wfp . G[b]) @ bk ----
  wfpg_kernel<<<4096, 256, 0, stream>>>(wfp_bf, G, wfpG);
  gemv_kernel<<<1024, 256, 0, stream>>>(wfpG, bk, cb, 16 * 256, 2048);
  gemm_kernel<5, 256, 2048><<<64, 512, 0, stream>>>(wfpG, wkT, 256, 2, 2, nullptr,
                                                    nullptr, Wc, nullptr, 524288, 256);

  // ---- dual consumer: out = x + attn ----
  dual_kernel<<<800, 512, 0, stream>>>(xn, wfq_bf, Wc, cfq, cb, cvec, rs_q, rs_k,
                                       x, out);

  // ---- LN2 (separate pass): out -> xn2 (into xn buffer) ----
  ln_kernel<<<(int)((kM + 3) / 4), 256, 0, stream>>>(out, n2w, n2b, xn, kM, nullptr,
                                                     nullptr, nullptr, nullptr,
                                                     nullptr, nullptr);

  // ---- MLP: hdn = gelu(xn2@w1^T+b1); out += hdn@w2^T+b2 ----
  gemm_kernel<3, 1024, 256><<<3144, 512, 0, stream>>>(xn, w1_bf, (int)kM, 8, 393,
                                                      b1, nullptr, hdn, nullptr, 0, 0);
  gemm_kernel<4, 256, 1024><<<786, 512, 0, stream>>>(hdn, w2_bf, (int)kM, 2, 393,
                                                     b2, xn, out, nullptr, 0, 0);
}